// Round 3
// baseline (766.070 us; speedup 1.0000x reference)
//
#include <hip/hip_runtime.h>

typedef unsigned int   u32;
typedef unsigned short u16;

// ---------- bf16 helpers ----------
__device__ __forceinline__ float bfs(u16 u) {
  union { u32 i; float f; } v; v.i = ((u32)u) << 16; return v.f;
}
__device__ __forceinline__ u16 f2bf(float f) {
  union { float f; u32 i; } v; v.f = f;
  u32 r = v.i + 0x7fffu + ((v.i >> 16) & 1u);   // RNE
  return (u16)(r >> 16);
}

// ---------------- Kernel 1: projections as per-head GEMM ----------------
// grid (token-tile=32, n-tile=4, head=16), 256 threads.
// Per head: [2048 tokens] x [256 outs] x K=64.  n-tile: 0=X 1=B 2=C 3=gate.
// Thread owns tokens ty*4+a (a<4) and cols tx+16c (c<4)  [b-frag 2-way-free reads]
__global__ __launch_bounds__(256) void k_proj(
    const float* __restrict__ inp,
    const float* __restrict__ W_XBC,  const float* __restrict__ b_XBC,
    const float* __restrict__ W_gate, const float* __restrict__ b_gate,
    u16* __restrict__ Xs, u16* __restrict__ Bms, u16* __restrict__ Cms,
    u16* __restrict__ gates)
{
  int tt = blockIdx.x, nt = blockIdx.y, h = blockIdx.z;
  int tid = threadIdx.x;
  int ty = tid >> 4, tx = tid & 15;
  int m0 = tt * 64, n0 = nt * 64;

  __shared__ float Xt[64][68];   // [token][k]
  __shared__ float Wt[64][68];   // [out][k]

#pragma unroll
  for (int i = 0; i < 4; ++i) {
    int f = tid + 256 * i;       // 0..1023 float4 slots
    int r = f >> 4, cq = f & 15;
    float4 xv = *(const float4*)(inp + (size_t)(m0 + r) * 1024 + h * 64 + 4 * cq);
    *(float4*)&Xt[r][4 * cq] = xv;
    int o = n0 + r;
    const float* wsrc = (o < 192) ? (W_XBC + ((size_t)h * 192 + o) * 64)
                                  : (W_gate + ((size_t)h * 64 + (o - 192)) * 64);
    float4 wv = *(const float4*)(wsrc + 4 * cq);
    *(float4*)&Wt[r][4 * cq] = wv;
  }
  __syncthreads();

  float acc[4][4];
#pragma unroll
  for (int a = 0; a < 4; ++a)
#pragma unroll
    for (int c = 0; c < 4; ++c) acc[a][c] = 0.f;

#pragma unroll
  for (int k4 = 0; k4 < 16; ++k4) {
    float4 xv[4], wv[4];
#pragma unroll
    for (int a = 0; a < 4; ++a) xv[a] = *(float4*)&Xt[ty * 4 + a][k4 * 4];
#pragma unroll
    for (int c = 0; c < 4; ++c) wv[c] = *(float4*)&Wt[tx + 16 * c][k4 * 4];
#pragma unroll
    for (int a = 0; a < 4; ++a)
#pragma unroll
      for (int c = 0; c < 4; ++c)
        acc[a][c] += xv[a].x * wv[c].x + xv[a].y * wv[c].y
                   + xv[a].z * wv[c].z + xv[a].w * wv[c].w;
  }

  // epilogue
  u16* dst = (nt == 0) ? Xs : (nt == 1) ? Bms : (nt == 2) ? Cms : gates;
#pragma unroll
  for (int a = 0; a < 4; ++a) {
    int mt = m0 + ty * 4 + a;
    if (nt < 3) {
      int b = mt >> 10, t = mt & 1023;
      size_t base = (((size_t)(b * 16 + h)) * 1024 + t) * 64;
#pragma unroll
      for (int c = 0; c < 4; ++c) {
        int n = tx + 16 * c;
        float v = acc[a][c] + b_XBC[h * 192 + n0 + n];
        v = v / (1.f + __expf(-v));           // silu
        dst[base + n] = f2bf(v);
      }
    } else {
      size_t base = ((size_t)mt * 16 + h) * 64;
#pragma unroll
      for (int c = 0; c < 4; ++c) {
        int n = tx + 16 * c;
        float v = acc[a][c] + b_gate[h * 64 + n];
        dst[base + n] = f2bf(v);
      }
    }
  }
}

// ---------------- Kernel 2: fused logA dot + inclusive cumsum ----------------
__global__ __launch_bounds__(1024) void k_scan(
    const float* __restrict__ inp, const float* __restrict__ W_logA,
    const float* __restrict__ b_logA, float* __restrict__ logAs)
{
  int bh = blockIdx.x;           // 32 = B*H
  int b = bh >> 4, h = bh & 15;
  int t = threadIdx.x;
  __shared__ float w[64];
  __shared__ float buf0[1024], buf1[1024];
  if (t < 64) w[t] = W_logA[h * 64 + t];
  __syncthreads();
  const float4* xr = (const float4*)(inp + ((size_t)(b * 1024 + t)) * 1024 + h * 64);
  float acc = b_logA[h];
#pragma unroll
  for (int i = 0; i < 16; ++i) {
    float4 v = xr[i];
    acc += v.x * w[4 * i] + v.y * w[4 * i + 1] + v.z * w[4 * i + 2] + v.w * w[4 * i + 3];
  }
  buf0[t] = acc;
  __syncthreads();
  float* src = buf0; float* dstp = buf1;
  for (int off = 1; off < 1024; off <<= 1) {
    float v = src[t];
    if (t >= off) v += src[t - off];
    dstp[t] = v;
    __syncthreads();
    float* tmp = src; src = dstp; dstp = tmp;
  }
  logAs[bh * 1024 + t] = src[t];
}

// ---------------- Kernel 3: causal SSM attention (tiled 64x64) ----------------
// phase1 col map: j = tx+16c (2-way-free b128 B reads); phase2 col map: c = tx*4+cc.
__global__ __launch_bounds__(256) void k_ssm(
    const u16* __restrict__ Xs, const u16* __restrict__ Bms, const u16* __restrict__ Cms,
    const float* __restrict__ cum, const u16* __restrict__ gates, u16* __restrict__ Yg)
{
  int it = gridDim.x - 1 - blockIdx.x;   // big tiles first
  int h = blockIdx.y, b = blockIdx.z;
  int bh = b * 16 + h;
  const u16* Xb = Xs  + (size_t)bh * 1024 * 64;
  const u16* Bb = Bms + (size_t)bh * 1024 * 64;
  const u16* Cb = Cms + (size_t)bh * 1024 * 64;
  const float* cumb = cum + bh * 1024;
  int tid = threadIdx.x;
  int ty = tid >> 4, tx = tid & 15;

  __shared__ float Cts[64][68];
  __shared__ float Bts[64][68];
  __shared__ float Sts[64][68];
  __shared__ u16   Xts[64][72];
  __shared__ float cumi[64], cumj[64];

  float acc[4][4];
#pragma unroll
  for (int a = 0; a < 4; ++a)
#pragma unroll
    for (int c = 0; c < 4; ++c) acc[a][c] = 0.f;

  int i0 = it * 64;
#pragma unroll
  for (int i = 0; i < 4; ++i) {
    int f = tid + 256 * i;       // ushort4 slots: 4096/4 = 1024
    int r = f >> 4, cq = f & 15;
    ushort4 v = *(const ushort4*)(Cb + (size_t)(i0 + r) * 64 + 4 * cq);
    Cts[r][4 * cq + 0] = bfs(v.x); Cts[r][4 * cq + 1] = bfs(v.y);
    Cts[r][4 * cq + 2] = bfs(v.z); Cts[r][4 * cq + 3] = bfs(v.w);
  }
  if (tid < 64) cumi[tid] = cumb[i0 + tid];
  __syncthreads();

  for (int jt = 0; jt <= it; ++jt) {
    int j0 = jt * 64;
#pragma unroll
    for (int i = 0; i < 4; ++i) {
      int f = tid + 256 * i;
      int r = f >> 4, cq = f & 15;
      ushort4 bv = *(const ushort4*)(Bb + (size_t)(j0 + r) * 64 + 4 * cq);
      Bts[r][4 * cq + 0] = bfs(bv.x); Bts[r][4 * cq + 1] = bfs(bv.y);
      Bts[r][4 * cq + 2] = bfs(bv.z); Bts[r][4 * cq + 3] = bfs(bv.w);
      *(ushort4*)&Xts[r][4 * cq] = *(const ushort4*)(Xb + (size_t)(j0 + r) * 64 + 4 * cq);
    }
    if (tid < 64) cumj[tid] = cumb[j0 + tid];
    __syncthreads();

    // phase 1: S[i][j] = exp(cum_i - cum_j) * dot_n(C[i], B[j]), causal-masked
    float sreg[4][4];
#pragma unroll
    for (int a = 0; a < 4; ++a)
#pragma unroll
      for (int c = 0; c < 4; ++c) sreg[a][c] = 0.f;
#pragma unroll
    for (int n4 = 0; n4 < 16; ++n4) {
      float4 cv[4], bv[4];
#pragma unroll
      for (int a = 0; a < 4; ++a) cv[a] = *(float4*)&Cts[ty * 4 + a][n4 * 4];
#pragma unroll
      for (int c = 0; c < 4; ++c) bv[c] = *(float4*)&Bts[tx + 16 * c][n4 * 4];
#pragma unroll
      for (int a = 0; a < 4; ++a)
#pragma unroll
        for (int c = 0; c < 4; ++c)
          sreg[a][c] += cv[a].x * bv[c].x + cv[a].y * bv[c].y
                      + cv[a].z * bv[c].z + cv[a].w * bv[c].w;
    }
#pragma unroll
    for (int a = 0; a < 4; ++a) {
      int i = ty * 4 + a;
      float ci = cumi[i];
#pragma unroll
      for (int c = 0; c < 4; ++c) {
        int j = tx + 16 * c;
        float v;
        if (jt == it && j > i) v = 0.f;   // mask before multiply
        else v = sreg[a][c] * __expf(fminf(ci - cumj[j], 30.f));
        Sts[i][j] = v;
      }
    }
    __syncthreads();

    // phase 2: Y[i][c] += sum_j S[i][j] * X[j][c]
#pragma unroll
    for (int j4 = 0; j4 < 16; ++j4) {
      float4 sv[4];
#pragma unroll
      for (int a = 0; a < 4; ++a) sv[a] = *(float4*)&Sts[ty * 4 + a][j4 * 4];
      float xv[4][4];
#pragma unroll
      for (int jj = 0; jj < 4; ++jj) {
        ushort4 xr = *(ushort4*)&Xts[j4 * 4 + jj][tx * 4];
        xv[jj][0] = bfs(xr.x); xv[jj][1] = bfs(xr.y);
        xv[jj][2] = bfs(xr.z); xv[jj][3] = bfs(xr.w);
      }
#pragma unroll
      for (int a = 0; a < 4; ++a)
#pragma unroll
        for (int c = 0; c < 4; ++c)
          acc[a][c] += sv[a].x * xv[0][c] + sv[a].y * xv[1][c]
                     + sv[a].z * xv[2][c] + sv[a].w * xv[3][c];
    }
    __syncthreads();
  }

  // epilogue: Yg = gate * Y, (B,T,D) bf16
#pragma unroll
  for (int a = 0; a < 4; ++a) {
    int i = i0 + ty * 4 + a;
    ushort4 gv = *(const ushort4*)(gates + (((size_t)(b * 1024 + i)) * 16 + h) * 64 + tx * 4);
    ushort4 pv;
    pv.x = f2bf(acc[a][0] * bfs(gv.x));
    pv.y = f2bf(acc[a][1] * bfs(gv.y));
    pv.z = f2bf(acc[a][2] * bfs(gv.z));
    pv.w = f2bf(acc[a][3] * bfs(gv.w));
    *(ushort4*)(Yg + ((size_t)(b * 1024 + i)) * 1024 + h * 64 + tx * 4) = pv;
  }
}

// ---------------- Kernel 4: out = Yg @ W_out^T + b_out ----------------
// M=2048, N=1024, K=1024. grid (32,16). cols owned as tx+16c.
__global__ __launch_bounds__(256) void k_out(
    const u16* __restrict__ Yg, const float* __restrict__ Wout,
    const float* __restrict__ bout, float* __restrict__ out)
{
  int bm = blockIdx.x, bn = blockIdx.y;
  int tid = threadIdx.x;
  int ty = tid >> 4, tx = tid & 15;
  __shared__ float Yt[64][68];
  __shared__ float Wt[64][68];
  float acc[4][4];
#pragma unroll
  for (int a = 0; a < 4; ++a)
#pragma unroll
    for (int c = 0; c < 4; ++c) acc[a][c] = 0.f;

  int m0 = bm * 64, d0 = bn * 64;
  for (int kt = 0; kt < 16; ++kt) {
    int k0 = kt * 64;
#pragma unroll
    for (int i = 0; i < 4; ++i) {
      int f = tid + 256 * i;
      int r = f >> 4, cq = f & 15;
      ushort4 yv = *(const ushort4*)(Yg + (size_t)(m0 + r) * 1024 + k0 + 4 * cq);
      float4 yf; yf.x = bfs(yv.x); yf.y = bfs(yv.y); yf.z = bfs(yv.z); yf.w = bfs(yv.w);
      *(float4*)&Yt[r][4 * cq] = yf;
      float4 wv = *(const float4*)(Wout + (size_t)(d0 + r) * 1024 + k0 + 4 * cq);
      *(float4*)&Wt[r][4 * cq] = wv;
    }
    __syncthreads();
#pragma unroll
    for (int k4 = 0; k4 < 16; ++k4) {
      float4 yv[4], wv[4];
#pragma unroll
      for (int a = 0; a < 4; ++a) yv[a] = *(float4*)&Yt[ty * 4 + a][k4 * 4];
#pragma unroll
      for (int c = 0; c < 4; ++c) wv[c] = *(float4*)&Wt[tx + 16 * c][k4 * 4];
#pragma unroll
      for (int a = 0; a < 4; ++a)
#pragma unroll
        for (int c = 0; c < 4; ++c)
          acc[a][c] += yv[a].x * wv[c].x + yv[a].y * wv[c].y
                     + yv[a].z * wv[c].z + yv[a].w * wv[c].w;
    }
    __syncthreads();
  }
#pragma unroll
  for (int a = 0; a < 4; ++a) {
    int m = m0 + ty * 4 + a;
#pragma unroll
    for (int c = 0; c < 4; ++c) {
      int n = tx + 16 * c;
      out[(size_t)m * 1024 + d0 + n] = acc[a][c] + bout[d0 + n];
    }
  }
}

// ---------------- host launcher ----------------
extern "C" void kernel_launch(void* const* d_in, const int* in_sizes, int n_in,
                              void* d_out, int out_size, void* d_ws, size_t ws_size,
                              hipStream_t stream)
{
  const float* inp   = (const float*)d_in[0];
  const float* WlogA = (const float*)d_in[1];
  const float* blogA = (const float*)d_in[2];
  const float* WXBC  = (const float*)d_in[3];
  const float* bXBC  = (const float*)d_in[4];
  const float* Wgate = (const float*)d_in[5];
  const float* bgate = (const float*)d_in[6];
  const float* Wout  = (const float*)d_in[7];
  const float* bout  = (const float*)d_in[8];
  float* out = (float*)d_out;

  const size_t SZ = (size_t)2 * 16 * 1024 * 64;  // 2,097,152 elements
  float* logAs = (float*)d_ws;
  u16* base16  = (u16*)(logAs + 32768);
  u16* Xs    = base16;
  u16* Bms   = Xs + SZ;
  u16* Cms   = Bms + SZ;
  u16* gates = Cms + SZ;
  u16* Yg    = gates + SZ;

  k_proj<<<dim3(32, 4, 16), 256, 0, stream>>>(inp, WXBC, bXBC, Wgate, bgate,
                                              Xs, Bms, Cms, gates);
  k_scan<<<32, 1024, 0, stream>>>(inp, WlogA, blogA, logAs);
  k_ssm<<<dim3(16, 16, 2), 256, 0, stream>>>(Xs, Bms, Cms, logAs, gates, Yg);
  k_out<<<dim3(32, 16), 256, 0, stream>>>(Yg, Wout, bout, out);
}

// Round 4
// 169.030 us; speedup vs baseline: 4.5322x; 4.5322x over previous
//
#include <hip/hip_runtime.h>

typedef unsigned int   u32;
typedef unsigned short u16;
typedef __attribute__((ext_vector_type(8))) short bf16x8;
typedef __attribute__((ext_vector_type(4))) float f32x4;

// ---------- bf16 helpers ----------
__device__ __forceinline__ float bfs(u16 u) {
  union { u32 i; float f; } v; v.i = ((u32)u) << 16; return v.f;
}
__device__ __forceinline__ u16 f2bf(float f) {
  union { float f; u32 i; } v; v.f = f;
  u32 r = v.i + 0x7fffu + ((v.i >> 16) & 1u);   // RNE
  return (u16)(r >> 16);
}

// ---------------- Kernel 1: projections as per-head GEMM (VALU) ----------------
// grid (token-tile=32, n-tile=4, head=16), 256 threads.
// X is written TRANSPOSED: X^T[bh][c][t] (t contiguous) for k_ssm B-operand reads.
__global__ __launch_bounds__(256) void k_proj(
    const float* __restrict__ inp,
    const float* __restrict__ W_XBC,  const float* __restrict__ b_XBC,
    const float* __restrict__ W_gate, const float* __restrict__ b_gate,
    u16* __restrict__ XsT, u16* __restrict__ Bms, u16* __restrict__ Cms,
    u16* __restrict__ gates)
{
  int tt = blockIdx.x, nt = blockIdx.y, h = blockIdx.z;
  int tid = threadIdx.x;
  int ty = tid >> 4, tx = tid & 15;
  int m0 = tt * 64, n0 = nt * 64;

  __shared__ float Xt[64][68];   // [token][k]
  __shared__ float Wt[64][68];   // [out][k]

#pragma unroll
  for (int i = 0; i < 4; ++i) {
    int f = tid + 256 * i;
    int r = f >> 4, cq = f & 15;
    float4 xv = *(const float4*)(inp + (size_t)(m0 + r) * 1024 + h * 64 + 4 * cq);
    *(float4*)&Xt[r][4 * cq] = xv;
    int o = n0 + r;
    const float* wsrc = (o < 192) ? (W_XBC + ((size_t)h * 192 + o) * 64)
                                  : (W_gate + ((size_t)h * 64 + (o - 192)) * 64);
    *(float4*)&Wt[r][4 * cq] = *(const float4*)(wsrc + 4 * cq);
  }
  __syncthreads();

  float acc[4][4];
#pragma unroll
  for (int a = 0; a < 4; ++a)
#pragma unroll
    for (int c = 0; c < 4; ++c) acc[a][c] = 0.f;

#pragma unroll
  for (int k4 = 0; k4 < 16; ++k4) {
    float4 xv[4], wv[4];
#pragma unroll
    for (int a = 0; a < 4; ++a) xv[a] = *(float4*)&Xt[ty * 4 + a][k4 * 4];
#pragma unroll
    for (int c = 0; c < 4; ++c) wv[c] = *(float4*)&Wt[tx + 16 * c][k4 * 4];
#pragma unroll
    for (int a = 0; a < 4; ++a)
#pragma unroll
      for (int c = 0; c < 4; ++c)
        acc[a][c] += xv[a].x * wv[c].x + xv[a].y * wv[c].y
                   + xv[a].z * wv[c].z + xv[a].w * wv[c].w;
  }

  if (nt == 0) {
    // X: silu, write transposed X^T[bh][n][t] packed over the 4 consecutive tokens
    int b = m0 >> 10;
    int t0 = (m0 & 1023) + ty * 4;
#pragma unroll
    for (int c = 0; c < 4; ++c) {
      int n = tx + 16 * c;
      float bias = b_XBC[h * 192 + n];
      ushort4 pv; u16 vs[4];
#pragma unroll
      for (int a = 0; a < 4; ++a) {
        float v = acc[a][c] + bias;
        v = v / (1.f + __expf(-v));
        vs[a] = f2bf(v);
      }
      pv.x = vs[0]; pv.y = vs[1]; pv.z = vs[2]; pv.w = vs[3];
      *(ushort4*)(XsT + ((size_t)(b * 16 + h) * 64 + n) * 1024 + t0) = pv;
    }
  } else if (nt < 3) {
    u16* dst = (nt == 1) ? Bms : Cms;
#pragma unroll
    for (int a = 0; a < 4; ++a) {
      int mt = m0 + ty * 4 + a;
      int b = mt >> 10, t = mt & 1023;
      size_t base = (((size_t)(b * 16 + h)) * 1024 + t) * 64;
#pragma unroll
      for (int c = 0; c < 4; ++c) {
        int n = tx + 16 * c;
        float v = acc[a][c] + b_XBC[h * 192 + n0 + n];
        v = v / (1.f + __expf(-v));
        dst[base + n] = f2bf(v);
      }
    }
  } else {
#pragma unroll
    for (int a = 0; a < 4; ++a) {
      int mt = m0 + ty * 4 + a;
      size_t base = ((size_t)mt * 16 + h) * 64;
#pragma unroll
      for (int c = 0; c < 4; ++c) {
        int n = tx + 16 * c;
        gates[base + n] = f2bf(acc[a][c] + b_gate[h * 64 + n]);
      }
    }
  }
}

// ---------------- Kernel 2: fused logA dot + inclusive cumsum ----------------
__global__ __launch_bounds__(1024) void k_scan(
    const float* __restrict__ inp, const float* __restrict__ W_logA,
    const float* __restrict__ b_logA, float* __restrict__ logAs)
{
  int bh = blockIdx.x;
  int b = bh >> 4, h = bh & 15;
  int t = threadIdx.x;
  __shared__ float w[64];
  __shared__ float buf0[1024], buf1[1024];
  if (t < 64) w[t] = W_logA[h * 64 + t];
  __syncthreads();
  const float4* xr = (const float4*)(inp + ((size_t)(b * 1024 + t)) * 1024 + h * 64);
  float acc = b_logA[h];
#pragma unroll
  for (int i = 0; i < 16; ++i) {
    float4 v = xr[i];
    acc += v.x * w[4 * i] + v.y * w[4 * i + 1] + v.z * w[4 * i + 2] + v.w * w[4 * i + 3];
  }
  buf0[t] = acc;
  __syncthreads();
  float* src = buf0; float* dstp = buf1;
  for (int off = 1; off < 1024; off <<= 1) {
    float v = src[t];
    if (t >= off) v += src[t - off];
    dstp[t] = v;
    __syncthreads();
    float* tmp = src; src = dstp; dstp = tmp;
  }
  logAs[bh * 1024 + t] = src[t];
}

// ---------------- Kernel 3: causal SSM attention — MFMA 16x16x32 bf16 ----------
// Block = 4 waves, 64x64 Y tile. Wave w owns row strip [16w,16w+16).
// S=C·Bm^T (MFMA) -> exp/causal scale in C/D regs -> Sts LDS (bf16) -> Y+=S·X (MFMA).
__global__ __launch_bounds__(256) void k_ssm(
    const u16* __restrict__ XsT, const u16* __restrict__ Bms, const u16* __restrict__ Cms,
    const float* __restrict__ cum, const u16* __restrict__ gates, u16* __restrict__ Yg)
{
  int g = blockIdx.x >> 5;              // 0..15
  int bh = blockIdx.x & 31;
  int it = (g & 1) ? (g >> 1) : (15 - (g >> 1));  // pair heavy with light
  int b = bh >> 4, h = bh & 15;

  const u16* Xb = XsT + (size_t)bh * 64 * 1024;   // [c][t]
  const u16* Bb = Bms + (size_t)bh * 1024 * 64;   // [t][n]
  const u16* Cb = Cms + (size_t)bh * 1024 * 64;
  const float* cumb = cum + bh * 1024;

  int tid = threadIdx.x;
  int w = tid >> 6, l = tid & 63, q = l >> 4, lr = l & 15;

  __shared__ u16 Cts[64][72];
  __shared__ u16 Bts[64][72];
  __shared__ u16 Xts[64][72];   // [c][j] (j contiguous)
  __shared__ u16 Sts[64][72];   // [i][j]
  __shared__ float cumi[64], cumj[64];

  int i0 = it * 64;
#pragma unroll
  for (int i = 0; i < 4; ++i) {
    int f = tid + 256 * i; int r = f >> 4, cq = f & 15;
    *(ushort4*)&Cts[r][4 * cq] = *(const ushort4*)(Cb + (size_t)(i0 + r) * 64 + 4 * cq);
  }
  if (tid < 64) cumi[tid] = cumb[i0 + tid];
  __syncthreads();

  bf16x8 ca0 = *(const bf16x8*)&Cts[16 * w + lr][q * 8];
  bf16x8 ca1 = *(const bf16x8*)&Cts[16 * w + lr][32 + q * 8];

  f32x4 acc[4];
#pragma unroll
  for (int ct = 0; ct < 4; ++ct) acc[ct] = (f32x4){0.f, 0.f, 0.f, 0.f};

  for (int jt = 0; jt <= it; ++jt) {
    int j0 = jt * 64;
    __syncthreads();   // previous phase2 reads done before restage
#pragma unroll
    for (int i = 0; i < 4; ++i) {
      int f = tid + 256 * i; int r = f >> 4, cq = f & 15;
      *(ushort4*)&Bts[r][4 * cq] = *(const ushort4*)(Bb + (size_t)(j0 + r) * 64 + 4 * cq);
      *(ushort4*)&Xts[r][4 * cq] = *(const ushort4*)(Xb + (size_t)r * 1024 + j0 + 4 * cq);
    }
    if (tid < 64) cumj[tid] = cumb[j0 + tid];
    __syncthreads();

    // phase 1: S strip
    bool diag = (jt == it);
#pragma unroll
    for (int ct = 0; ct < 4; ++ct) {
      f32x4 s = (f32x4){0.f, 0.f, 0.f, 0.f};
      bf16x8 b0 = *(const bf16x8*)&Bts[16 * ct + lr][q * 8];
      bf16x8 b1 = *(const bf16x8*)&Bts[16 * ct + lr][32 + q * 8];
      s = __builtin_amdgcn_mfma_f32_16x16x32_bf16(ca0, b0, s, 0, 0, 0);
      s = __builtin_amdgcn_mfma_f32_16x16x32_bf16(ca1, b1, s, 0, 0, 0);
      int jl = 16 * ct + lr;
      float cj = cumj[jl];
#pragma unroll
      for (int r = 0; r < 4; ++r) {
        int il = 16 * w + q * 4 + r;
        float v;
        if (diag && jl > il) v = 0.f;
        else v = s[r] * __expf(fminf(cumi[il] - cj, 30.f));
        Sts[il][jl] = f2bf(v);
      }
    }

    // phase 2: Y strip += S·X (same-wave rows; per-wave in-order DS => no barrier)
    bf16x8 sa0 = *(const bf16x8*)&Sts[16 * w + lr][q * 8];
    bf16x8 sa1 = *(const bf16x8*)&Sts[16 * w + lr][32 + q * 8];
#pragma unroll
    for (int ct = 0; ct < 4; ++ct) {
      bf16x8 x0 = *(const bf16x8*)&Xts[16 * ct + lr][q * 8];
      bf16x8 x1 = *(const bf16x8*)&Xts[16 * ct + lr][32 + q * 8];
      acc[ct] = __builtin_amdgcn_mfma_f32_16x16x32_bf16(sa0, x0, acc[ct], 0, 0, 0);
      acc[ct] = __builtin_amdgcn_mfma_f32_16x16x32_bf16(sa1, x1, acc[ct], 0, 0, 0);
    }
  }

  // epilogue: Yg = gate * Y, (B,T,D) bf16
#pragma unroll
  for (int ct = 0; ct < 4; ++ct) {
    int c = 16 * ct + lr;
#pragma unroll
    for (int r = 0; r < 4; ++r) {
      int tg = i0 + 16 * w + q * 4 + r;
      size_t row = (size_t)(b * 1024 + tg);
      float gt = bfs(gates[(row * 16 + h) * 64 + c]);
      Yg[row * 1024 + h * 64 + c] = f2bf(acc[ct][r] * gt);
    }
  }
}

// ---------------- Kernel 4: out = Yg @ W_out^T + b_out — MFMA ----------------
// grid (16,16): 128x64 tile. Wave w: rows [32w,32w+32) x 64 cols.
__global__ __launch_bounds__(256) void k_out(
    const u16* __restrict__ Yg, const float* __restrict__ Wout,
    const float* __restrict__ bout, float* __restrict__ out)
{
  int bm = blockIdx.x, bn = blockIdx.y;
  int tid = threadIdx.x;
  int w = tid >> 6, l = tid & 63, q = l >> 4, lr = l & 15;
  int m0 = bm * 128, d0 = bn * 64;

  __shared__ u16 Yt[128][72];
  __shared__ u16 Wt[64][72];

  f32x4 acc[2][4];
#pragma unroll
  for (int rt = 0; rt < 2; ++rt)
#pragma unroll
    for (int ct = 0; ct < 4; ++ct) acc[rt][ct] = (f32x4){0.f, 0.f, 0.f, 0.f};

  for (int kt = 0; kt < 16; ++kt) {
    int k0 = kt * 64;
#pragma unroll
    for (int i = 0; i < 8; ++i) {
      int f = tid + 256 * i; int r = f >> 4, cq = f & 15;
      *(ushort4*)&Yt[r][4 * cq] = *(const ushort4*)(Yg + (size_t)(m0 + r) * 1024 + k0 + 4 * cq);
    }
#pragma unroll
    for (int i = 0; i < 4; ++i) {
      int f = tid + 256 * i; int r = f >> 4, cq = f & 15;
      float4 wv = *(const float4*)(Wout + (size_t)(d0 + r) * 1024 + k0 + 4 * cq);
      ushort4 wp; wp.x = f2bf(wv.x); wp.y = f2bf(wv.y); wp.z = f2bf(wv.z); wp.w = f2bf(wv.w);
      *(ushort4*)&Wt[r][4 * cq] = wp;
    }
    __syncthreads();

    bf16x8 a00 = *(const bf16x8*)&Yt[32 * w + lr][q * 8];
    bf16x8 a01 = *(const bf16x8*)&Yt[32 * w + lr][32 + q * 8];
    bf16x8 a10 = *(const bf16x8*)&Yt[32 * w + 16 + lr][q * 8];
    bf16x8 a11 = *(const bf16x8*)&Yt[32 * w + 16 + lr][32 + q * 8];
#pragma unroll
    for (int ct = 0; ct < 4; ++ct) {
      bf16x8 b0 = *(const bf16x8*)&Wt[16 * ct + lr][q * 8];
      bf16x8 b1 = *(const bf16x8*)&Wt[16 * ct + lr][32 + q * 8];
      acc[0][ct] = __builtin_amdgcn_mfma_f32_16x16x32_bf16(a00, b0, acc[0][ct], 0, 0, 0);
      acc[0][ct] = __builtin_amdgcn_mfma_f32_16x16x32_bf16(a01, b1, acc[0][ct], 0, 0, 0);
      acc[1][ct] = __builtin_amdgcn_mfma_f32_16x16x32_bf16(a10, b0, acc[1][ct], 0, 0, 0);
      acc[1][ct] = __builtin_amdgcn_mfma_f32_16x16x32_bf16(a11, b1, acc[1][ct], 0, 0, 0);
    }
    __syncthreads();
  }

#pragma unroll
  for (int rt = 0; rt < 2; ++rt)
#pragma unroll
    for (int ct = 0; ct < 4; ++ct) {
      int d = d0 + 16 * ct + lr;
      float bo = bout[d];
#pragma unroll
      for (int r = 0; r < 4; ++r) {
        int m = m0 + 32 * w + 16 * rt + q * 4 + r;
        out[(size_t)m * 1024 + d] = acc[rt][ct][r] + bo;
      }
    }
}

// ---------------- host launcher ----------------
extern "C" void kernel_launch(void* const* d_in, const int* in_sizes, int n_in,
                              void* d_out, int out_size, void* d_ws, size_t ws_size,
                              hipStream_t stream)
{
  const float* inp   = (const float*)d_in[0];
  const float* WlogA = (const float*)d_in[1];
  const float* blogA = (const float*)d_in[2];
  const float* WXBC  = (const float*)d_in[3];
  const float* bXBC  = (const float*)d_in[4];
  const float* Wgate = (const float*)d_in[5];
  const float* bgate = (const float*)d_in[6];
  const float* Wout  = (const float*)d_in[7];
  const float* bout  = (const float*)d_in[8];
  float* out = (float*)d_out;

  const size_t SZ = (size_t)2 * 16 * 1024 * 64;  // 2,097,152 elements
  float* logAs = (float*)d_ws;
  u16* base16  = (u16*)(logAs + 32768);
  u16* XsT   = base16;          // [bh][c][t]
  u16* Bms   = XsT + SZ;        // [bh][t][n]
  u16* Cms   = Bms + SZ;
  u16* gates = Cms + SZ;        // [b,t,h,c]
  u16* Yg    = gates + SZ;      // [b,t,d]

  k_proj<<<dim3(32, 4, 16), 256, 0, stream>>>(inp, WXBC, bXBC, Wgate, bgate,
                                              XsT, Bms, Cms, gates);
  k_scan<<<32, 1024, 0, stream>>>(inp, WlogA, blogA, logAs);
  k_ssm<<<dim3(512), 256, 0, stream>>>(XsT, Bms, Cms, logAs, gates, Yg);
  k_out<<<dim3(16, 16), 256, 0, stream>>>(Yg, Wout, bout, out);
}

// Round 5
// 137.409 us; speedup vs baseline: 5.5751x; 1.2301x over previous
//
#include <hip/hip_runtime.h>

typedef unsigned int   u32;
typedef unsigned short u16;
typedef __attribute__((ext_vector_type(8))) short bf16x8;
typedef __attribute__((ext_vector_type(4))) float f32x4;

// ---------- bf16 helpers ----------
__device__ __forceinline__ float bfs(u16 u) {
  union { u32 i; float f; } v; v.i = ((u32)u) << 16; return v.f;
}
__device__ __forceinline__ u16 f2bf(float f) {
  union { float f; u32 i; } v; v.f = f;
  u32 r = v.i + 0x7fffu + ((v.i >> 16) & 1u);   // RNE
  return (u16)(r >> 16);
}
__device__ __forceinline__ ushort4 f2bf4(float4 v) {
  ushort4 p; p.x = f2bf(v.x); p.y = f2bf(v.y); p.z = f2bf(v.z); p.w = f2bf(v.w);
  return p;
}

// ---------------- Kernel 1: projections — MFMA 16x16x32 bf16 ----------------
// grid (token-tile=32, head=16), 256 threads (4 waves).
// Tile: 64 tokens x 256 outs (X|B|C|gate), K=64. Wave w owns out-group w.
// Also computes logA (wave-0 lanes) into logAs (pre-scan).
__global__ __launch_bounds__(256) void k_proj(
    const float* __restrict__ inp,
    const float* __restrict__ W_XBC,  const float* __restrict__ b_XBC,
    const float* __restrict__ W_gate, const float* __restrict__ b_gate,
    const float* __restrict__ W_logA, const float* __restrict__ b_logA,
    u16* __restrict__ XsT, u16* __restrict__ Bms, u16* __restrict__ Cms,
    u16* __restrict__ gates, float* __restrict__ logAs)
{
  int tt = blockIdx.x, h = blockIdx.y;
  int tid = threadIdx.x;
  int w = tid >> 6, l = tid & 63, q = l >> 4, lr = l & 15;
  int m0 = tt * 64;                 // global token base (tile never straddles batch)
  int b = m0 >> 10, tl0 = m0 & 1023;
  int bh = b * 16 + h;

  __shared__ u16 Xt[64][72];        // [token][k] bf16
  __shared__ u16 Wt[256][72];       // [out][k]  bf16 (0..191 XBC, 192..255 gate)
  __shared__ float wl[64];          // W_logA row

  if (tid < 64) wl[tid] = W_logA[h * 64 + tid];
#pragma unroll
  for (int i = 0; i < 4; ++i) {     // inp tile: 4096 f32
    int f = tid + 256 * i; int r = f >> 4, cq = f & 15;
    float4 xv = *(const float4*)(inp + (size_t)(m0 + r) * 1024 + h * 64 + 4 * cq);
    *(ushort4*)&Xt[r][4 * cq] = f2bf4(xv);
  }
#pragma unroll
  for (int i = 0; i < 16; ++i) {    // weights: 16384 f32
    int f = tid + 256 * i; int r = f >> 4, cq = f & 15;
    const float* wsrc = (r < 192) ? (W_XBC + ((size_t)h * 192 + r) * 64)
                                  : (W_gate + ((size_t)h * 64 + (r - 192)) * 64);
    *(ushort4*)&Wt[r][4 * cq] = f2bf4(*(const float4*)(wsrc + 4 * cq));
  }
  __syncthreads();

  // A-frags: 4 token row-tiles x 2 k-halves
  bf16x8 af[4][2];
#pragma unroll
  for (int rt = 0; rt < 4; ++rt) {
    af[rt][0] = *(const bf16x8*)&Xt[16 * rt + lr][q * 8];
    af[rt][1] = *(const bf16x8*)&Xt[16 * rt + lr][32 + q * 8];
  }

  f32x4 acc[4][4];
#pragma unroll
  for (int rt = 0; rt < 4; ++rt)
#pragma unroll
    for (int ct = 0; ct < 4; ++ct) acc[rt][ct] = (f32x4){0.f, 0.f, 0.f, 0.f};

#pragma unroll
  for (int ct = 0; ct < 4; ++ct) {
    bf16x8 b0 = *(const bf16x8*)&Wt[64 * w + 16 * ct + lr][q * 8];
    bf16x8 b1 = *(const bf16x8*)&Wt[64 * w + 16 * ct + lr][32 + q * 8];
#pragma unroll
    for (int rt = 0; rt < 4; ++rt) {
      acc[rt][ct] = __builtin_amdgcn_mfma_f32_16x16x32_bf16(af[rt][0], b0, acc[rt][ct], 0, 0, 0);
      acc[rt][ct] = __builtin_amdgcn_mfma_f32_16x16x32_bf16(af[rt][1], b1, acc[rt][ct], 0, 0, 0);
    }
  }

  // logA for this tile's 64 tokens (wave-0 lanes; bf16 inp, f32 math)
  if (tid < 64) {
    float a = b_logA[h];
#pragma unroll 16
    for (int k = 0; k < 64; ++k) a += bfs(Xt[tid][k]) * wl[k];
    logAs[(size_t)bh * 1024 + tl0 + tid] = a;
  }

  // epilogues (wave-uniform branch per out-group)
  if (w == 0) {
    // X: silu, transposed store X^T[bh][n][t]
#pragma unroll
    for (int ct = 0; ct < 4; ++ct) {
      int n = 16 * ct + lr;
      float bias = b_XBC[h * 192 + n];
#pragma unroll
      for (int rt = 0; rt < 4; ++rt) {
        float4 v;
#pragma unroll
        for (int r = 0; r < 4; ++r) {
          float s = acc[rt][ct][r] + bias;
          (&v.x)[r] = s / (1.f + __expf(-s));
        }
        *(ushort4*)(XsT + ((size_t)bh * 64 + n) * 1024 + tl0 + 16 * rt + q * 4) = f2bf4(v);
      }
    }
  } else if (w < 3) {
    u16* dst = (w == 1) ? Bms : Cms;
    int nbase = h * 192 + 64 * w;
#pragma unroll
    for (int ct = 0; ct < 4; ++ct) {
      int n = 16 * ct + lr;
      float bias = b_XBC[nbase + n];
#pragma unroll
      for (int rt = 0; rt < 4; ++rt)
#pragma unroll
        for (int r = 0; r < 4; ++r) {
          int tloc = tl0 + 16 * rt + q * 4 + r;
          float s = acc[rt][ct][r] + bias;
          s = s / (1.f + __expf(-s));
          dst[((size_t)bh * 1024 + tloc) * 64 + n] = f2bf(s);
        }
    }
  } else {
#pragma unroll
    for (int ct = 0; ct < 4; ++ct) {
      int n = 16 * ct + lr;
      float bias = b_gate[h * 64 + n];
#pragma unroll
      for (int rt = 0; rt < 4; ++rt)
#pragma unroll
        for (int r = 0; r < 4; ++r) {
          int tg = m0 + 16 * rt + q * 4 + r;
          gates[((size_t)tg * 16 + h) * 64 + n] = f2bf(acc[rt][ct][r] + bias);
        }
    }
  }
}

// ---------------- Kernel 2: pure inclusive cumsum over T per (b,h) ------------
__global__ __launch_bounds__(1024) void k_scan(float* __restrict__ logAs)
{
  int bh = blockIdx.x;
  int t = threadIdx.x;
  __shared__ float buf0[1024], buf1[1024];
  buf0[t] = logAs[(size_t)bh * 1024 + t];
  __syncthreads();
  float* src = buf0; float* dstp = buf1;
  for (int off = 1; off < 1024; off <<= 1) {
    float v = src[t];
    if (t >= off) v += src[t - off];
    dstp[t] = v;
    __syncthreads();
    float* tmp = src; src = dstp; dstp = tmp;
  }
  logAs[(size_t)bh * 1024 + t] = src[t];
}

// ---------------- Kernel 2b: Wout f32 -> bf16 (once) --------------------------
__global__ __launch_bounds__(256) void k_wconv(
    const float* __restrict__ Wout, u16* __restrict__ WoutB)
{
  int i = blockIdx.x * 256 + threadIdx.x;   // 262144 float4 slots
  float4 v = ((const float4*)Wout)[i];
  ((ushort4*)WoutB)[i] = f2bf4(v);
}

// ---------------- Kernel 3: causal SSM attention — MFMA 16x16x32 bf16 ----------
__global__ __launch_bounds__(256) void k_ssm(
    const u16* __restrict__ XsT, const u16* __restrict__ Bms, const u16* __restrict__ Cms,
    const float* __restrict__ cum, const u16* __restrict__ gates, u16* __restrict__ Yg)
{
  int g = blockIdx.x >> 5;
  int bh = blockIdx.x & 31;
  int it = (g & 1) ? (g >> 1) : (15 - (g >> 1));  // pair heavy with light
  int b = bh >> 4, h = bh & 15;

  const u16* Xb = XsT + (size_t)bh * 64 * 1024;   // [c][t]
  const u16* Bb = Bms + (size_t)bh * 1024 * 64;   // [t][n]
  const u16* Cb = Cms + (size_t)bh * 1024 * 64;
  const float* cumb = cum + bh * 1024;

  int tid = threadIdx.x;
  int w = tid >> 6, l = tid & 63, q = l >> 4, lr = l & 15;

  __shared__ u16 Cts[64][72];
  __shared__ u16 Bts[64][72];
  __shared__ u16 Xts[64][72];   // [c][j]
  __shared__ u16 Sts[64][72];   // [i][j]
  __shared__ float cumi[64], cumj[64];

  int i0 = it * 64;
#pragma unroll
  for (int i = 0; i < 4; ++i) {
    int f = tid + 256 * i; int r = f >> 4, cq = f & 15;
    *(ushort4*)&Cts[r][4 * cq] = *(const ushort4*)(Cb + (size_t)(i0 + r) * 64 + 4 * cq);
  }
  if (tid < 64) cumi[tid] = cumb[i0 + tid];
  __syncthreads();

  bf16x8 ca0 = *(const bf16x8*)&Cts[16 * w + lr][q * 8];
  bf16x8 ca1 = *(const bf16x8*)&Cts[16 * w + lr][32 + q * 8];

  f32x4 acc[4];
#pragma unroll
  for (int ct = 0; ct < 4; ++ct) acc[ct] = (f32x4){0.f, 0.f, 0.f, 0.f};

  for (int jt = 0; jt <= it; ++jt) {
    int j0 = jt * 64;
    __syncthreads();
#pragma unroll
    for (int i = 0; i < 4; ++i) {
      int f = tid + 256 * i; int r = f >> 4, cq = f & 15;
      *(ushort4*)&Bts[r][4 * cq] = *(const ushort4*)(Bb + (size_t)(j0 + r) * 64 + 4 * cq);
      *(ushort4*)&Xts[r][4 * cq] = *(const ushort4*)(Xb + (size_t)r * 1024 + j0 + 4 * cq);
    }
    if (tid < 64) cumj[tid] = cumb[j0 + tid];
    __syncthreads();

    bool diag = (jt == it);
#pragma unroll
    for (int ct = 0; ct < 4; ++ct) {
      f32x4 s = (f32x4){0.f, 0.f, 0.f, 0.f};
      bf16x8 b0 = *(const bf16x8*)&Bts[16 * ct + lr][q * 8];
      bf16x8 b1 = *(const bf16x8*)&Bts[16 * ct + lr][32 + q * 8];
      s = __builtin_amdgcn_mfma_f32_16x16x32_bf16(ca0, b0, s, 0, 0, 0);
      s = __builtin_amdgcn_mfma_f32_16x16x32_bf16(ca1, b1, s, 0, 0, 0);
      int jl = 16 * ct + lr;
      float cj = cumj[jl];
#pragma unroll
      for (int r = 0; r < 4; ++r) {
        int il = 16 * w + q * 4 + r;
        float v;
        if (diag && jl > il) v = 0.f;
        else v = s[r] * __expf(fminf(cumi[il] - cj, 30.f));
        Sts[il][jl] = f2bf(v);
      }
    }

    bf16x8 sa0 = *(const bf16x8*)&Sts[16 * w + lr][q * 8];
    bf16x8 sa1 = *(const bf16x8*)&Sts[16 * w + lr][32 + q * 8];
#pragma unroll
    for (int ct = 0; ct < 4; ++ct) {
      bf16x8 x0 = *(const bf16x8*)&Xts[16 * ct + lr][q * 8];
      bf16x8 x1 = *(const bf16x8*)&Xts[16 * ct + lr][32 + q * 8];
      acc[ct] = __builtin_amdgcn_mfma_f32_16x16x32_bf16(sa0, x0, acc[ct], 0, 0, 0);
      acc[ct] = __builtin_amdgcn_mfma_f32_16x16x32_bf16(sa1, x1, acc[ct], 0, 0, 0);
    }
  }

#pragma unroll
  for (int ct = 0; ct < 4; ++ct) {
    int c = 16 * ct + lr;
#pragma unroll
    for (int r = 0; r < 4; ++r) {
      int tg = i0 + 16 * w + q * 4 + r;
      size_t row = (size_t)(b * 1024 + tg);
      float gt = bfs(gates[(row * 16 + h) * 64 + c]);
      Yg[row * 1024 + h * 64 + c] = f2bf(acc[ct][r] * gt);
    }
  }
}

// ---------------- Kernel 4: out = Yg @ W_out^T + b_out — MFMA ----------------
__global__ __launch_bounds__(256) void k_out(
    const u16* __restrict__ Yg, const u16* __restrict__ WoutB,
    const float* __restrict__ bout, float* __restrict__ out)
{
  int bm = blockIdx.x, bn = blockIdx.y;
  int tid = threadIdx.x;
  int w = tid >> 6, l = tid & 63, q = l >> 4, lr = l & 15;
  int m0 = bm * 128, d0 = bn * 64;

  __shared__ u16 Yt[128][72];
  __shared__ u16 Wt[64][72];

  f32x4 acc[2][4];
#pragma unroll
  for (int rt = 0; rt < 2; ++rt)
#pragma unroll
    for (int ct = 0; ct < 4; ++ct) acc[rt][ct] = (f32x4){0.f, 0.f, 0.f, 0.f};

  for (int kt = 0; kt < 16; ++kt) {
    int k0 = kt * 64;
#pragma unroll
    for (int i = 0; i < 8; ++i) {
      int f = tid + 256 * i; int r = f >> 4, cq = f & 15;
      *(ushort4*)&Yt[r][4 * cq] = *(const ushort4*)(Yg + (size_t)(m0 + r) * 1024 + k0 + 4 * cq);
    }
#pragma unroll
    for (int i = 0; i < 4; ++i) {
      int f = tid + 256 * i; int r = f >> 4, cq = f & 15;
      *(ushort4*)&Wt[r][4 * cq] = *(const ushort4*)(WoutB + (size_t)(d0 + r) * 1024 + k0 + 4 * cq);
    }
    __syncthreads();

    bf16x8 a00 = *(const bf16x8*)&Yt[32 * w + lr][q * 8];
    bf16x8 a01 = *(const bf16x8*)&Yt[32 * w + lr][32 + q * 8];
    bf16x8 a10 = *(const bf16x8*)&Yt[32 * w + 16 + lr][q * 8];
    bf16x8 a11 = *(const bf16x8*)&Yt[32 * w + 16 + lr][32 + q * 8];
#pragma unroll
    for (int ct = 0; ct < 4; ++ct) {
      bf16x8 b0 = *(const bf16x8*)&Wt[16 * ct + lr][q * 8];
      bf16x8 b1 = *(const bf16x8*)&Wt[16 * ct + lr][32 + q * 8];
      acc[0][ct] = __builtin_amdgcn_mfma_f32_16x16x32_bf16(a00, b0, acc[0][ct], 0, 0, 0);
      acc[0][ct] = __builtin_amdgcn_mfma_f32_16x16x32_bf16(a01, b1, acc[0][ct], 0, 0, 0);
      acc[1][ct] = __builtin_amdgcn_mfma_f32_16x16x32_bf16(a10, b0, acc[1][ct], 0, 0, 0);
      acc[1][ct] = __builtin_amdgcn_mfma_f32_16x16x32_bf16(a11, b1, acc[1][ct], 0, 0, 0);
    }
    __syncthreads();
  }

#pragma unroll
  for (int rt = 0; rt < 2; ++rt)
#pragma unroll
    for (int ct = 0; ct < 4; ++ct) {
      int d = d0 + 16 * ct + lr;
      float bo = bout[d];
#pragma unroll
      for (int r = 0; r < 4; ++r) {
        int m = m0 + 32 * w + 16 * rt + q * 4 + r;
        out[(size_t)m * 1024 + d] = acc[rt][ct][r] + bo;
      }
    }
}

// ---------------- host launcher ----------------
extern "C" void kernel_launch(void* const* d_in, const int* in_sizes, int n_in,
                              void* d_out, int out_size, void* d_ws, size_t ws_size,
                              hipStream_t stream)
{
  const float* inp   = (const float*)d_in[0];
  const float* WlogA = (const float*)d_in[1];
  const float* blogA = (const float*)d_in[2];
  const float* WXBC  = (const float*)d_in[3];
  const float* bXBC  = (const float*)d_in[4];
  const float* Wgate = (const float*)d_in[5];
  const float* bgate = (const float*)d_in[6];
  const float* Wout  = (const float*)d_in[7];
  const float* bout  = (const float*)d_in[8];
  float* out = (float*)d_out;

  const size_t SZ = (size_t)2 * 16 * 1024 * 64;  // 2,097,152 elements
  float* logAs = (float*)d_ws;                   // 128 KiB
  u16* base16  = (u16*)(logAs + 32768);
  u16* XsT   = base16;          // [bh][c][t]      4 MiB
  u16* Bms   = XsT + SZ;        // [bh][t][n]      4 MiB
  u16* Cms   = Bms + SZ;        //                 4 MiB
  u16* gates = Cms + SZ;        // [b,t,h,c]       4 MiB
  u16* Yg    = gates + SZ;      // [b,t,d]         4 MiB
  u16* WoutB = Yg + SZ;         // bf16 Wout       2 MiB   (total ~22.1 MiB)

  k_proj<<<dim3(32, 16), 256, 0, stream>>>(inp, WXBC, bXBC, Wgate, bgate,
                                           WlogA, blogA, XsT, Bms, Cms, gates, logAs);
  k_scan<<<32, 1024, 0, stream>>>(logAs);
  k_wconv<<<1024, 256, 0, stream>>>(Wout, WoutB);
  k_ssm<<<dim3(512), 256, 0, stream>>>(XsT, Bms, Cms, logAs, gates, Yg);
  k_out<<<dim3(16, 16), 256, 0, stream>>>(Yg, WoutB, bout, out);
}

// Round 6
// 128.909 us; speedup vs baseline: 5.9427x; 1.0659x over previous
//
#include <hip/hip_runtime.h>

typedef unsigned int   u32;
typedef unsigned short u16;
typedef __attribute__((ext_vector_type(8))) short bf16x8;
typedef __attribute__((ext_vector_type(4))) float f32x4;

// ---------- bf16 helpers ----------
__device__ __forceinline__ float bfs(u16 u) {
  union { u32 i; float f; } v; v.i = ((u32)u) << 16; return v.f;
}
__device__ __forceinline__ u16 f2bf(float f) {
  union { float f; u32 i; } v; v.f = f;
  u32 r = v.i + 0x7fffu + ((v.i >> 16) & 1u);   // RNE
  return (u16)(r >> 16);
}
__device__ __forceinline__ ushort4 f2bf4(float4 v) {
  ushort4 p; p.x = f2bf(v.x); p.y = f2bf(v.y); p.z = f2bf(v.z); p.w = f2bf(v.w);
  return p;
}

// ---------------- Kernel 1: projections — MFMA 16x16x32 bf16 ----------------
// grid (token-tile=32, head=16), 256 threads (4 waves).
__global__ __launch_bounds__(256) void k_proj(
    const float* __restrict__ inp,
    const float* __restrict__ W_XBC,  const float* __restrict__ b_XBC,
    const float* __restrict__ W_gate, const float* __restrict__ b_gate,
    const float* __restrict__ W_logA, const float* __restrict__ b_logA,
    u16* __restrict__ XsT, u16* __restrict__ Bms, u16* __restrict__ Cms,
    u16* __restrict__ gates, float* __restrict__ logAs)
{
  int tt = blockIdx.x, h = blockIdx.y;
  int tid = threadIdx.x;
  int w = tid >> 6, l = tid & 63, q = l >> 4, lr = l & 15;
  int m0 = tt * 64;
  int b = m0 >> 10, tl0 = m0 & 1023;
  int bh = b * 16 + h;

  __shared__ u16 Xt[64][72];
  __shared__ u16 Wt[256][72];
  __shared__ float wl[64];

  if (tid < 64) wl[tid] = W_logA[h * 64 + tid];
#pragma unroll
  for (int i = 0; i < 4; ++i) {
    int f = tid + 256 * i; int r = f >> 4, cq = f & 15;
    float4 xv = *(const float4*)(inp + (size_t)(m0 + r) * 1024 + h * 64 + 4 * cq);
    *(ushort4*)&Xt[r][4 * cq] = f2bf4(xv);
  }
#pragma unroll
  for (int i = 0; i < 16; ++i) {
    int f = tid + 256 * i; int r = f >> 4, cq = f & 15;
    const float* wsrc = (r < 192) ? (W_XBC + ((size_t)h * 192 + r) * 64)
                                  : (W_gate + ((size_t)h * 64 + (r - 192)) * 64);
    *(ushort4*)&Wt[r][4 * cq] = f2bf4(*(const float4*)(wsrc + 4 * cq));
  }
  __syncthreads();

  bf16x8 af[4][2];
#pragma unroll
  for (int rt = 0; rt < 4; ++rt) {
    af[rt][0] = *(const bf16x8*)&Xt[16 * rt + lr][q * 8];
    af[rt][1] = *(const bf16x8*)&Xt[16 * rt + lr][32 + q * 8];
  }

  f32x4 acc[4][4];
#pragma unroll
  for (int rt = 0; rt < 4; ++rt)
#pragma unroll
    for (int ct = 0; ct < 4; ++ct) acc[rt][ct] = (f32x4){0.f, 0.f, 0.f, 0.f};

#pragma unroll
  for (int ct = 0; ct < 4; ++ct) {
    bf16x8 b0 = *(const bf16x8*)&Wt[64 * w + 16 * ct + lr][q * 8];
    bf16x8 b1 = *(const bf16x8*)&Wt[64 * w + 16 * ct + lr][32 + q * 8];
#pragma unroll
    for (int rt = 0; rt < 4; ++rt) {
      acc[rt][ct] = __builtin_amdgcn_mfma_f32_16x16x32_bf16(af[rt][0], b0, acc[rt][ct], 0, 0, 0);
      acc[rt][ct] = __builtin_amdgcn_mfma_f32_16x16x32_bf16(af[rt][1], b1, acc[rt][ct], 0, 0, 0);
    }
  }

  if (tid < 64) {
    float a = b_logA[h];
#pragma unroll 16
    for (int k = 0; k < 64; ++k) a += bfs(Xt[tid][k]) * wl[k];
    logAs[(size_t)bh * 1024 + tl0 + tid] = a;
  }

  if (w == 0) {
#pragma unroll
    for (int ct = 0; ct < 4; ++ct) {
      int n = 16 * ct + lr;
      float bias = b_XBC[h * 192 + n];
#pragma unroll
      for (int rt = 0; rt < 4; ++rt) {
        float4 v;
#pragma unroll
        for (int r = 0; r < 4; ++r) {
          float s = acc[rt][ct][r] + bias;
          (&v.x)[r] = s / (1.f + __expf(-s));
        }
        *(ushort4*)(XsT + ((size_t)bh * 64 + n) * 1024 + tl0 + 16 * rt + q * 4) = f2bf4(v);
      }
    }
  } else if (w < 3) {
    u16* dst = (w == 1) ? Bms : Cms;
    int nbase = h * 192 + 64 * w;
#pragma unroll
    for (int ct = 0; ct < 4; ++ct) {
      int n = 16 * ct + lr;
      float bias = b_XBC[nbase + n];
#pragma unroll
      for (int rt = 0; rt < 4; ++rt)
#pragma unroll
        for (int r = 0; r < 4; ++r) {
          int tloc = tl0 + 16 * rt + q * 4 + r;
          float s = acc[rt][ct][r] + bias;
          s = s / (1.f + __expf(-s));
          dst[((size_t)bh * 1024 + tloc) * 64 + n] = f2bf(s);
        }
    }
  } else {
#pragma unroll
    for (int ct = 0; ct < 4; ++ct) {
      int n = 16 * ct + lr;
      float bias = b_gate[h * 64 + n];
#pragma unroll
      for (int rt = 0; rt < 4; ++rt)
#pragma unroll
        for (int r = 0; r < 4; ++r) {
          int tg = m0 + 16 * rt + q * 4 + r;
          gates[((size_t)tg * 16 + h) * 64 + n] = f2bf(acc[rt][ct][r] + bias);
        }
    }
  }
}

// ---------------- Kernel 2: shuffle scan + exp factor tables -----------------
// cumsum over T per (b,h); emits rowexp=exp(cum), colexp=exp(-cum).
__global__ __launch_bounds__(1024) void k_scan(
    const float* __restrict__ logAs, float* __restrict__ rowexp,
    float* __restrict__ colexp)
{
  int bh = blockIdx.x;
  int t = threadIdx.x;
  int wv = t >> 6, ln = t & 63;
  __shared__ float wsum[16];
  float v = logAs[(size_t)bh * 1024 + t];
#pragma unroll
  for (int off = 1; off < 64; off <<= 1) {
    float n = __shfl_up(v, off, 64);
    if (ln >= off) v += n;
  }
  if (ln == 63) wsum[wv] = v;
  __syncthreads();
  if (wv == 0) {
    float s = (ln < 16) ? wsum[ln] : 0.f;
#pragma unroll
    for (int off = 1; off < 16; off <<= 1) {
      float n = __shfl_up(s, off, 64);
      if (ln >= off) s += n;
    }
    if (ln < 16) wsum[ln] = s;
  }
  __syncthreads();
  if (wv > 0) v += wsum[wv - 1];
  rowexp[(size_t)bh * 1024 + t] = __expf(v);
  colexp[(size_t)bh * 1024 + t] = __expf(-v);
}

// ---------------- Kernel 2b: Wout f32 -> bf16 (once) --------------------------
__global__ __launch_bounds__(256) void k_wconv(
    const float* __restrict__ Wout, u16* __restrict__ WoutB)
{
  int i = blockIdx.x * 256 + threadIdx.x;
  float4 v = ((const float4*)Wout)[i];
  ((ushort4*)WoutB)[i] = f2bf4(v);
}

// ---------------- Kernel 3: causal SSM — MFMA, exp-factored, prefetched -------
__global__ __launch_bounds__(256) void k_ssm(
    const u16* __restrict__ XsT, const u16* __restrict__ Bms, const u16* __restrict__ Cms,
    const float* __restrict__ rowexp, const float* __restrict__ colexp,
    const u16* __restrict__ gates, u16* __restrict__ Yg)
{
  int g = blockIdx.x >> 5;
  int bh = blockIdx.x & 31;
  int it = (g & 1) ? (g >> 1) : (15 - (g >> 1));  // pair heavy with light
  int b = bh >> 4, h = bh & 15;

  const u16* Xb = XsT + (size_t)bh * 64 * 1024;   // [c][t]
  const u16* Bb = Bms + (size_t)bh * 1024 * 64;   // [t][n]
  const u16* Cb = Cms + (size_t)bh * 1024 * 64;

  int tid = threadIdx.x;
  int w = tid >> 6, l = tid & 63, q = l >> 4, lr = l & 15;

  __shared__ u16 Cts[64][72];
  __shared__ u16 Bts[64][72];
  __shared__ u16 Xts[64][72];
  __shared__ u16 Sts[64][72];
  __shared__ float ref_[64], cef[64];

  int i0 = it * 64;
#pragma unroll
  for (int i = 0; i < 4; ++i) {
    int f = tid + 256 * i; int r = f >> 4, cq = f & 15;
    *(ushort4*)&Cts[r][4 * cq] = *(const ushort4*)(Cb + (size_t)(i0 + r) * 64 + 4 * cq);
  }
  if (tid < 64) ref_[tid] = rowexp[(size_t)bh * 1024 + i0 + tid];
  __syncthreads();

  bf16x8 ca0 = *(const bf16x8*)&Cts[16 * w + lr][q * 8];
  bf16x8 ca1 = *(const bf16x8*)&Cts[16 * w + lr][32 + q * 8];

  f32x4 acc[4];
#pragma unroll
  for (int ct = 0; ct < 4; ++ct) acc[ct] = (f32x4){0.f, 0.f, 0.f, 0.f};

  // prefetch jt=0
  ushort4 pb[4], px[4]; float pce = 0.f;
#pragma unroll
  for (int i = 0; i < 4; ++i) {
    int f = tid + 256 * i; int r = f >> 4, cq = f & 15;
    pb[i] = *(const ushort4*)(Bb + (size_t)r * 64 + 4 * cq);
    px[i] = *(const ushort4*)(Xb + (size_t)r * 1024 + 4 * cq);
  }
  if (tid < 64) pce = colexp[(size_t)bh * 1024 + tid];

  for (int jt = 0; jt <= it; ++jt) {
    __syncthreads();   // prior phase1/2 LDS reads done before overwrite
#pragma unroll
    for (int i = 0; i < 4; ++i) {
      int f = tid + 256 * i; int r = f >> 4, cq = f & 15;
      *(ushort4*)&Bts[r][4 * cq] = pb[i];
      *(ushort4*)&Xts[r][4 * cq] = px[i];
    }
    if (tid < 64) cef[tid] = pce;
    __syncthreads();

    if (jt < it) {     // prefetch next tile while MFMAs run
      int j1 = (jt + 1) * 64;
#pragma unroll
      for (int i = 0; i < 4; ++i) {
        int f = tid + 256 * i; int r = f >> 4, cq = f & 15;
        pb[i] = *(const ushort4*)(Bb + (size_t)(j1 + r) * 64 + 4 * cq);
        px[i] = *(const ushort4*)(Xb + (size_t)r * 1024 + j1 + 4 * cq);
      }
      if (tid < 64) pce = colexp[(size_t)bh * 1024 + j1 + tid];
    }

    bool diag = (jt == it);
#pragma unroll
    for (int ct = 0; ct < 4; ++ct) {
      f32x4 s = (f32x4){0.f, 0.f, 0.f, 0.f};
      bf16x8 b0 = *(const bf16x8*)&Bts[16 * ct + lr][q * 8];
      bf16x8 b1 = *(const bf16x8*)&Bts[16 * ct + lr][32 + q * 8];
      s = __builtin_amdgcn_mfma_f32_16x16x32_bf16(ca0, b0, s, 0, 0, 0);
      s = __builtin_amdgcn_mfma_f32_16x16x32_bf16(ca1, b1, s, 0, 0, 0);
      int jl = 16 * ct + lr;
      float cj = cef[jl];
#pragma unroll
      for (int r = 0; r < 4; ++r) {
        int il = 16 * w + q * 4 + r;
        float v = (diag && jl > il) ? 0.f : s[r] * ref_[il] * cj;
        Sts[il][jl] = f2bf(v);
      }
    }

    // phase 2 (same-wave Sts rows: no barrier needed)
    bf16x8 sa0 = *(const bf16x8*)&Sts[16 * w + lr][q * 8];
    bf16x8 sa1 = *(const bf16x8*)&Sts[16 * w + lr][32 + q * 8];
#pragma unroll
    for (int ct = 0; ct < 4; ++ct) {
      bf16x8 x0 = *(const bf16x8*)&Xts[16 * ct + lr][q * 8];
      bf16x8 x1 = *(const bf16x8*)&Xts[16 * ct + lr][32 + q * 8];
      acc[ct] = __builtin_amdgcn_mfma_f32_16x16x32_bf16(sa0, x0, acc[ct], 0, 0, 0);
      acc[ct] = __builtin_amdgcn_mfma_f32_16x16x32_bf16(sa1, x1, acc[ct], 0, 0, 0);
    }
  }

#pragma unroll
  for (int ct = 0; ct < 4; ++ct) {
    int c = 16 * ct + lr;
#pragma unroll
    for (int r = 0; r < 4; ++r) {
      int tg = i0 + 16 * w + q * 4 + r;
      size_t row = (size_t)(b * 1024 + tg);
      float gt = bfs(gates[(row * 16 + h) * 64 + c]);
      Yg[row * 1024 + h * 64 + c] = f2bf(acc[ct][r] * gt);
    }
  }
}

// ---------------- Kernel 4: out = Yg @ W_out^T + b_out — MFMA, 8 waves -------
// grid (16,16): 128x64 tile, 512 threads. Wave w owns rows [16w,16w+16).
__global__ __launch_bounds__(512) void k_out(
    const u16* __restrict__ Yg, const u16* __restrict__ WoutB,
    const float* __restrict__ bout, float* __restrict__ out)
{
  int bm = blockIdx.x, bn = blockIdx.y;
  int tid = threadIdx.x;
  int w = tid >> 6, l = tid & 63, q = l >> 4, lr = l & 15;
  int m0 = bm * 128, d0 = bn * 64;

  __shared__ u16 Yt[128][72];
  __shared__ u16 Wt[64][72];

  f32x4 acc[4];
#pragma unroll
  for (int ct = 0; ct < 4; ++ct) acc[ct] = (f32x4){0.f, 0.f, 0.f, 0.f};

  // prefetch kt=0
  ushort4 py[4], pw[2];
#pragma unroll
  for (int i = 0; i < 4; ++i) {
    int f = tid + 512 * i; int r = f >> 4, cq = f & 15;
    py[i] = *(const ushort4*)(Yg + (size_t)(m0 + r) * 1024 + 4 * cq);
  }
#pragma unroll
  for (int i = 0; i < 2; ++i) {
    int f = tid + 512 * i; int r = f >> 4, cq = f & 15;
    pw[i] = *(const ushort4*)(WoutB + (size_t)(d0 + r) * 1024 + 4 * cq);
  }

  for (int kt = 0; kt < 16; ++kt) {
    __syncthreads();
#pragma unroll
    for (int i = 0; i < 4; ++i) {
      int f = tid + 512 * i; int r = f >> 4, cq = f & 15;
      *(ushort4*)&Yt[r][4 * cq] = py[i];
    }
#pragma unroll
    for (int i = 0; i < 2; ++i) {
      int f = tid + 512 * i; int r = f >> 4, cq = f & 15;
      *(ushort4*)&Wt[r][4 * cq] = pw[i];
    }
    __syncthreads();

    if (kt < 15) {
      int k1 = (kt + 1) * 64;
#pragma unroll
      for (int i = 0; i < 4; ++i) {
        int f = tid + 512 * i; int r = f >> 4, cq = f & 15;
        py[i] = *(const ushort4*)(Yg + (size_t)(m0 + r) * 1024 + k1 + 4 * cq);
      }
#pragma unroll
      for (int i = 0; i < 2; ++i) {
        int f = tid + 512 * i; int r = f >> 4, cq = f & 15;
        pw[i] = *(const ushort4*)(WoutB + (size_t)(d0 + r) * 1024 + k1 + 4 * cq);
      }
    }

    bf16x8 a0 = *(const bf16x8*)&Yt[16 * w + lr][q * 8];
    bf16x8 a1 = *(const bf16x8*)&Yt[16 * w + lr][32 + q * 8];
#pragma unroll
    for (int ct = 0; ct < 4; ++ct) {
      bf16x8 b0 = *(const bf16x8*)&Wt[16 * ct + lr][q * 8];
      bf16x8 b1 = *(const bf16x8*)&Wt[16 * ct + lr][32 + q * 8];
      acc[ct] = __builtin_amdgcn_mfma_f32_16x16x32_bf16(a0, b0, acc[ct], 0, 0, 0);
      acc[ct] = __builtin_amdgcn_mfma_f32_16x16x32_bf16(a1, b1, acc[ct], 0, 0, 0);
    }
  }

#pragma unroll
  for (int ct = 0; ct < 4; ++ct) {
    int d = d0 + 16 * ct + lr;
    float bo = bout[d];
#pragma unroll
    for (int r = 0; r < 4; ++r) {
      int m = m0 + 16 * w + q * 4 + r;
      out[(size_t)m * 1024 + d] = acc[ct][r] + bo;
    }
  }
}

// ---------------- host launcher ----------------
extern "C" void kernel_launch(void* const* d_in, const int* in_sizes, int n_in,
                              void* d_out, int out_size, void* d_ws, size_t ws_size,
                              hipStream_t stream)
{
  const float* inp   = (const float*)d_in[0];
  const float* WlogA = (const float*)d_in[1];
  const float* blogA = (const float*)d_in[2];
  const float* WXBC  = (const float*)d_in[3];
  const float* bXBC  = (const float*)d_in[4];
  const float* Wgate = (const float*)d_in[5];
  const float* bgate = (const float*)d_in[6];
  const float* Wout  = (const float*)d_in[7];
  const float* bout  = (const float*)d_in[8];
  float* out = (float*)d_out;

  const size_t SZ = (size_t)2 * 16 * 1024 * 64;  // 2,097,152 elements
  float* logAs  = (float*)d_ws;                  // 128 KiB
  float* rowexp = logAs + 32768;                 // 128 KiB
  float* colexp = rowexp + 32768;                // 128 KiB
  u16* base16  = (u16*)(colexp + 32768);
  u16* XsT   = base16;          // [bh][c][t]      4 MiB
  u16* Bms   = XsT + SZ;        // [bh][t][n]      4 MiB
  u16* Cms   = Bms + SZ;        //                 4 MiB
  u16* gates = Cms + SZ;        // [b,t,h,c]       4 MiB
  u16* Yg    = gates + SZ;      // [b,t,d]         4 MiB
  u16* WoutB = Yg + SZ;         // bf16 Wout       2 MiB

  k_proj<<<dim3(32, 16), 256, 0, stream>>>(inp, WXBC, bXBC, Wgate, bgate,
                                           WlogA, blogA, XsT, Bms, Cms, gates, logAs);
  k_scan<<<32, 1024, 0, stream>>>(logAs, rowexp, colexp);
  k_wconv<<<1024, 256, 0, stream>>>(Wout, WoutB);
  k_ssm<<<dim3(512), 256, 0, stream>>>(XsT, Bms, Cms, rowexp, colexp, gates, Yg);
  k_out<<<dim3(16, 16), 512, 0, stream>>>(Yg, WoutB, bout, out);
}

// Round 7
// 128.394 us; speedup vs baseline: 5.9666x; 1.0040x over previous
//
#include <hip/hip_runtime.h>

typedef unsigned int   u32;
typedef unsigned short u16;
typedef __attribute__((ext_vector_type(8))) short bf16x8;
typedef __attribute__((ext_vector_type(4))) float f32x4;

// ---------- bf16 helpers ----------
__device__ __forceinline__ float bfs(u16 u) {
  union { u32 i; float f; } v; v.i = ((u32)u) << 16; return v.f;
}
__device__ __forceinline__ u16 f2bf(float f) {
  union { float f; u32 i; } v; v.f = f;
  u32 r = v.i + 0x7fffu + ((v.i >> 16) & 1u);   // RNE
  return (u16)(r >> 16);
}
__device__ __forceinline__ ushort4 f2bf4(float4 v) {
  ushort4 p; p.x = f2bf(v.x); p.y = f2bf(v.y); p.z = f2bf(v.z); p.w = f2bf(v.w);
  return p;
}

// ---------------- Kernel 1: projections — MFMA 16x16x32 bf16 ----------------
// grid (token-tile=32, head=16), 256 threads (4 waves).
// Writes: XsT [bh][c][t], Bms [bh][t][n], BmsT [bh][n][t], Cms [bh][t][n],
// gates [b,t,h,c], logAs (pre-scan).
__global__ __launch_bounds__(256) void k_proj(
    const float* __restrict__ inp,
    const float* __restrict__ W_XBC,  const float* __restrict__ b_XBC,
    const float* __restrict__ W_gate, const float* __restrict__ b_gate,
    const float* __restrict__ W_logA, const float* __restrict__ b_logA,
    u16* __restrict__ XsT, u16* __restrict__ Bms, u16* __restrict__ BmsT,
    u16* __restrict__ Cms, u16* __restrict__ gates, float* __restrict__ logAs)
{
  int tt = blockIdx.x, h = blockIdx.y;
  int tid = threadIdx.x;
  int w = tid >> 6, l = tid & 63, q = l >> 4, lr = l & 15;
  int m0 = tt * 64;
  int b = m0 >> 10, tl0 = m0 & 1023;
  int bh = b * 16 + h;

  __shared__ u16 Xt[64][72];
  __shared__ u16 Wt[256][72];
  __shared__ float wl[64];

  if (tid < 64) wl[tid] = W_logA[h * 64 + tid];
#pragma unroll
  for (int i = 0; i < 4; ++i) {
    int f = tid + 256 * i; int r = f >> 4, cq = f & 15;
    float4 xv = *(const float4*)(inp + (size_t)(m0 + r) * 1024 + h * 64 + 4 * cq);
    *(ushort4*)&Xt[r][4 * cq] = f2bf4(xv);
  }
#pragma unroll
  for (int i = 0; i < 16; ++i) {
    int f = tid + 256 * i; int r = f >> 4, cq = f & 15;
    const float* wsrc = (r < 192) ? (W_XBC + ((size_t)h * 192 + r) * 64)
                                  : (W_gate + ((size_t)h * 64 + (r - 192)) * 64);
    *(ushort4*)&Wt[r][4 * cq] = f2bf4(*(const float4*)(wsrc + 4 * cq));
  }
  __syncthreads();

  bf16x8 af[4][2];
#pragma unroll
  for (int rt = 0; rt < 4; ++rt) {
    af[rt][0] = *(const bf16x8*)&Xt[16 * rt + lr][q * 8];
    af[rt][1] = *(const bf16x8*)&Xt[16 * rt + lr][32 + q * 8];
  }

  f32x4 acc[4][4];
#pragma unroll
  for (int rt = 0; rt < 4; ++rt)
#pragma unroll
    for (int ct = 0; ct < 4; ++ct) acc[rt][ct] = (f32x4){0.f, 0.f, 0.f, 0.f};

#pragma unroll
  for (int ct = 0; ct < 4; ++ct) {
    bf16x8 b0 = *(const bf16x8*)&Wt[64 * w + 16 * ct + lr][q * 8];
    bf16x8 b1 = *(const bf16x8*)&Wt[64 * w + 16 * ct + lr][32 + q * 8];
#pragma unroll
    for (int rt = 0; rt < 4; ++rt) {
      acc[rt][ct] = __builtin_amdgcn_mfma_f32_16x16x32_bf16(af[rt][0], b0, acc[rt][ct], 0, 0, 0);
      acc[rt][ct] = __builtin_amdgcn_mfma_f32_16x16x32_bf16(af[rt][1], b1, acc[rt][ct], 0, 0, 0);
    }
  }

  if (tid < 64) {
    float a = b_logA[h];
#pragma unroll 16
    for (int k = 0; k < 64; ++k) a += bfs(Xt[tid][k]) * wl[k];
    logAs[(size_t)bh * 1024 + tl0 + tid] = a;
  }

  if (w == 0) {
    // X: silu, transposed store X^T[bh][n][t]
#pragma unroll
    for (int ct = 0; ct < 4; ++ct) {
      int n = 16 * ct + lr;
      float bias = b_XBC[h * 192 + n];
#pragma unroll
      for (int rt = 0; rt < 4; ++rt) {
        float4 v;
#pragma unroll
        for (int r = 0; r < 4; ++r) {
          float s = acc[rt][ct][r] + bias;
          (&v.x)[r] = s / (1.f + __expf(-s));
        }
        *(ushort4*)(XsT + ((size_t)bh * 64 + n) * 1024 + tl0 + 16 * rt + q * 4) = f2bf4(v);
      }
    }
  } else if (w == 1) {
    // B: silu, write both [t][n] and transposed [n][t]
#pragma unroll
    for (int ct = 0; ct < 4; ++ct) {
      int n = 16 * ct + lr;
      float bias = b_XBC[h * 192 + 64 + n];
#pragma unroll
      for (int rt = 0; rt < 4; ++rt) {
        float4 v;
#pragma unroll
        for (int r = 0; r < 4; ++r) {
          float s = acc[rt][ct][r] + bias;
          (&v.x)[r] = s / (1.f + __expf(-s));
        }
        ushort4 pv = f2bf4(v);
        *(ushort4*)(BmsT + ((size_t)bh * 64 + n) * 1024 + tl0 + 16 * rt + q * 4) = pv;
        u16 vs[4] = {pv.x, pv.y, pv.z, pv.w};
#pragma unroll
        for (int r = 0; r < 4; ++r) {
          int tloc = tl0 + 16 * rt + q * 4 + r;
          Bms[((size_t)bh * 1024 + tloc) * 64 + n] = vs[r];
        }
      }
    }
  } else if (w == 2) {
#pragma unroll
    for (int ct = 0; ct < 4; ++ct) {
      int n = 16 * ct + lr;
      float bias = b_XBC[h * 192 + 128 + n];
#pragma unroll
      for (int rt = 0; rt < 4; ++rt)
#pragma unroll
        for (int r = 0; r < 4; ++r) {
          int tloc = tl0 + 16 * rt + q * 4 + r;
          float s = acc[rt][ct][r] + bias;
          s = s / (1.f + __expf(-s));
          Cms[((size_t)bh * 1024 + tloc) * 64 + n] = f2bf(s);
        }
    }
  } else {
#pragma unroll
    for (int ct = 0; ct < 4; ++ct) {
      int n = 16 * ct + lr;
      float bias = b_gate[h * 64 + n];
#pragma unroll
      for (int rt = 0; rt < 4; ++rt)
#pragma unroll
        for (int r = 0; r < 4; ++r) {
          int tg = m0 + 16 * rt + q * 4 + r;
          gates[((size_t)tg * 16 + h) * 64 + n] = f2bf(acc[rt][ct][r] + bias);
        }
    }
  }
}

// ---------------- Kernel 2: shuffle scan + exp tables + fused Wout conv ------
__global__ __launch_bounds__(1024) void k_scan(
    const float* __restrict__ logAs, float* __restrict__ rowexp,
    float* __restrict__ colexp,
    const float* __restrict__ Wout, u16* __restrict__ WoutB)
{
  int bh = blockIdx.x;
  int t = threadIdx.x;
  int wv = t >> 6, ln = t & 63;
  __shared__ float wsum[16];
  float v = logAs[(size_t)bh * 1024 + t];
#pragma unroll
  for (int off = 1; off < 64; off <<= 1) {
    float n = __shfl_up(v, off, 64);
    if (ln >= off) v += n;
  }
  if (ln == 63) wsum[wv] = v;
  __syncthreads();
  if (wv == 0) {
    float s = (ln < 16) ? wsum[ln] : 0.f;
#pragma unroll
    for (int off = 1; off < 16; off <<= 1) {
      float n = __shfl_up(s, off, 64);
      if (ln >= off) s += n;
    }
    if (ln < 16) wsum[ln] = s;
  }
  __syncthreads();
  if (wv > 0) v += wsum[wv - 1];
  rowexp[(size_t)bh * 1024 + t] = __expf(v);
  colexp[(size_t)bh * 1024 + t] = __expf(-v);

  // fused Wout f32->bf16: 262144 float4 over 32768 threads
  int gtid = bh * 1024 + t;
#pragma unroll
  for (int i = 0; i < 8; ++i) {
    int idx = gtid + 32768 * i;
    float4 wv4 = ((const float4*)Wout)[idx];
    ((ushort4*)WoutB)[idx] = f2bf4(wv4);
  }
}

// ---------------- Kernel 3a: per-tile state G = B^T·diag(colexp)·X ----------
// grid (jt=16, bh=32), 256 threads. G[bh][jt][n][c] f32.
__global__ __launch_bounds__(256) void k_state(
    const u16* __restrict__ XsT, const u16* __restrict__ BmsT,
    const float* __restrict__ colexp, float* __restrict__ G)
{
  int jt = blockIdx.x, bh = blockIdx.y;
  int tid = threadIdx.x;
  int w = tid >> 6, l = tid & 63, q = l >> 4, lr = l & 15;
  int j0 = jt * 64;

  __shared__ u16 Bt[64][72];    // [n][j]
  __shared__ u16 Xt[64][72];    // [c][j] scaled by colexp_j

#pragma unroll
  for (int i = 0; i < 4; ++i) {
    int f = tid + 256 * i; int r = f >> 4, cq = f & 15;
    *(ushort4*)&Bt[r][4 * cq] =
        *(const ushort4*)(BmsT + ((size_t)bh * 64 + r) * 1024 + j0 + 4 * cq);
    ushort4 xv = *(const ushort4*)(XsT + ((size_t)bh * 64 + r) * 1024 + j0 + 4 * cq);
    float4 ce = *(const float4*)(colexp + (size_t)bh * 1024 + j0 + 4 * cq);
    float4 sv;
    sv.x = bfs(xv.x) * ce.x; sv.y = bfs(xv.y) * ce.y;
    sv.z = bfs(xv.z) * ce.z; sv.w = bfs(xv.w) * ce.w;
    *(ushort4*)&Xt[r][4 * cq] = f2bf4(sv);
  }
  __syncthreads();

  bf16x8 a0 = *(const bf16x8*)&Bt[16 * w + lr][q * 8];
  bf16x8 a1 = *(const bf16x8*)&Bt[16 * w + lr][32 + q * 8];

  f32x4 acc[4];
#pragma unroll
  for (int ct = 0; ct < 4; ++ct) acc[ct] = (f32x4){0.f, 0.f, 0.f, 0.f};
#pragma unroll
  for (int ct = 0; ct < 4; ++ct) {
    bf16x8 b0 = *(const bf16x8*)&Xt[16 * ct + lr][q * 8];
    bf16x8 b1 = *(const bf16x8*)&Xt[16 * ct + lr][32 + q * 8];
    acc[ct] = __builtin_amdgcn_mfma_f32_16x16x32_bf16(a0, b0, acc[ct], 0, 0, 0);
    acc[ct] = __builtin_amdgcn_mfma_f32_16x16x32_bf16(a1, b1, acc[ct], 0, 0, 0);
  }

  float* Gt = G + ((size_t)bh * 16 + jt) * 4096;
#pragma unroll
  for (int ct = 0; ct < 4; ++ct)
#pragma unroll
    for (int r = 0; r < 4; ++r)
      Gt[(16 * w + q * 4 + r) * 64 + 16 * ct + lr] = acc[ct][r];
}

// ---------------- Kernel 3b: exclusive prefix of G, transposed bf16 out ------
// grid 32 (bh), 1024 threads. HpreT[bh][it][c][n] bf16.
__global__ __launch_bounds__(1024) void k_prefix(
    const float* __restrict__ G, u16* __restrict__ HpreT)
{
  int bh = blockIdx.x;
  int tid = threadIdx.x;
  __shared__ float buf[64][65];
  float h[4] = {0.f, 0.f, 0.f, 0.f};
  for (int it = 0; it < 16; ++it) {
    size_t base = ((size_t)bh * 16 + it) * 4096;
#pragma unroll
    for (int k = 0; k < 4; ++k) {
      int e = tid + 1024 * k;       // flat [n][c]
      buf[e >> 6][e & 63] = h[k];
    }
    __syncthreads();
#pragma unroll
    for (int k = 0; k < 4; ++k) {
      int e = tid + 1024 * k;       // flat out [c][n]
      int c = e >> 6, n = e & 63;
      HpreT[base + e] = f2bf(buf[n][c]);
      h[k] += G[base + e];          // accumulate this tile (post-write: exclusive)
    }
    __syncthreads();
  }
}

// ---------------- Kernel 3c: diagonal quadratic + C·Hpre — MFMA --------------
// grid (it=16, bh=32), 256 threads. Single barrier, perfectly balanced.
__global__ __launch_bounds__(256) void k_ssm2(
    const u16* __restrict__ XsT, const u16* __restrict__ Bms, const u16* __restrict__ Cms,
    const float* __restrict__ rowexp, const float* __restrict__ colexp,
    const u16* __restrict__ HpreT, const u16* __restrict__ gates, u16* __restrict__ Yg)
{
  int it = blockIdx.x, bh = blockIdx.y;
  int b = bh >> 4, h = bh & 15;
  int tid = threadIdx.x;
  int w = tid >> 6, l = tid & 63, q = l >> 4, lr = l & 15;
  int i0 = it * 64;

  __shared__ u16 Cts[64][72];
  __shared__ u16 Bts[64][72];
  __shared__ u16 Xts[64][72];   // [c][j] diag tile
  __shared__ u16 Sts[64][72];
  __shared__ u16 HTt[64][72];   // [c][n]
  __shared__ float ref_[64], cef[64];

  const u16* Cb = Cms + (size_t)bh * 1024 * 64;
  const u16* Bb = Bms + (size_t)bh * 1024 * 64;
  const u16* Xb = XsT + (size_t)bh * 64 * 1024;
  const u16* Hb = HpreT + ((size_t)bh * 16 + it) * 4096;

#pragma unroll
  for (int i = 0; i < 4; ++i) {
    int f = tid + 256 * i; int r = f >> 4, cq = f & 15;
    *(ushort4*)&Cts[r][4 * cq] = *(const ushort4*)(Cb + (size_t)(i0 + r) * 64 + 4 * cq);
    *(ushort4*)&Bts[r][4 * cq] = *(const ushort4*)(Bb + (size_t)(i0 + r) * 64 + 4 * cq);
    *(ushort4*)&Xts[r][4 * cq] = *(const ushort4*)(Xb + (size_t)r * 1024 + i0 + 4 * cq);
    *(ushort4*)&HTt[r][4 * cq] = *(const ushort4*)(Hb + r * 64 + 4 * cq);
  }
  if (tid < 64) {
    ref_[tid] = rowexp[(size_t)bh * 1024 + i0 + tid];
    cef[tid]  = colexp[(size_t)bh * 1024 + i0 + tid];
  }
  __syncthreads();

  bf16x8 ca0 = *(const bf16x8*)&Cts[16 * w + lr][q * 8];
  bf16x8 ca1 = *(const bf16x8*)&Cts[16 * w + lr][32 + q * 8];

  // phase 1: diagonal S tile (causal-masked, exp-scaled)
#pragma unroll
  for (int ct = 0; ct < 4; ++ct) {
    f32x4 s = (f32x4){0.f, 0.f, 0.f, 0.f};
    bf16x8 b0 = *(const bf16x8*)&Bts[16 * ct + lr][q * 8];
    bf16x8 b1 = *(const bf16x8*)&Bts[16 * ct + lr][32 + q * 8];
    s = __builtin_amdgcn_mfma_f32_16x16x32_bf16(ca0, b0, s, 0, 0, 0);
    s = __builtin_amdgcn_mfma_f32_16x16x32_bf16(ca1, b1, s, 0, 0, 0);
    int jl = 16 * ct + lr;
    float cj = cef[jl];
#pragma unroll
    for (int r = 0; r < 4; ++r) {
      int il = 16 * w + q * 4 + r;
      float v = (jl > il) ? 0.f : s[r] * ref_[il] * cj;
      Sts[il][jl] = f2bf(v);
    }
  }

  // phase 2+3: Y = S·X_diag + diag(rowexp)·(C·Hpre)   (same-wave Sts rows)
  bf16x8 sa0 = *(const bf16x8*)&Sts[16 * w + lr][q * 8];
  bf16x8 sa1 = *(const bf16x8*)&Sts[16 * w + lr][32 + q * 8];
  f32x4 accd[4], acco[4];
#pragma unroll
  for (int ct = 0; ct < 4; ++ct) {
    accd[ct] = (f32x4){0.f, 0.f, 0.f, 0.f};
    acco[ct] = (f32x4){0.f, 0.f, 0.f, 0.f};
    bf16x8 x0 = *(const bf16x8*)&Xts[16 * ct + lr][q * 8];
    bf16x8 x1 = *(const bf16x8*)&Xts[16 * ct + lr][32 + q * 8];
    accd[ct] = __builtin_amdgcn_mfma_f32_16x16x32_bf16(sa0, x0, accd[ct], 0, 0, 0);
    accd[ct] = __builtin_amdgcn_mfma_f32_16x16x32_bf16(sa1, x1, accd[ct], 0, 0, 0);
    bf16x8 h0 = *(const bf16x8*)&HTt[16 * ct + lr][q * 8];
    bf16x8 h1 = *(const bf16x8*)&HTt[16 * ct + lr][32 + q * 8];
    acco[ct] = __builtin_amdgcn_mfma_f32_16x16x32_bf16(ca0, h0, acco[ct], 0, 0, 0);
    acco[ct] = __builtin_amdgcn_mfma_f32_16x16x32_bf16(ca1, h1, acco[ct], 0, 0, 0);
  }

  // epilogue: gate & store
#pragma unroll
  for (int ct = 0; ct < 4; ++ct) {
    int c = 16 * ct + lr;
#pragma unroll
    for (int r = 0; r < 4; ++r) {
      int il = 16 * w + q * 4 + r;
      int tg = i0 + il;
      size_t row = (size_t)(b * 1024 + tg);
      float y = accd[ct][r] + ref_[il] * acco[ct][r];
      float gt = bfs(gates[(row * 16 + h) * 64 + c]);
      Yg[row * 1024 + h * 64 + c] = f2bf(y * gt);
    }
  }
}

// ---------------- Kernel 4: out = Yg @ W_out^T + b_out — MFMA, 8 waves -------
__global__ __launch_bounds__(512) void k_out(
    const u16* __restrict__ Yg, const u16* __restrict__ WoutB,
    const float* __restrict__ bout, float* __restrict__ out)
{
  int bm = blockIdx.x, bn = blockIdx.y;
  int tid = threadIdx.x;
  int w = tid >> 6, l = tid & 63, q = l >> 4, lr = l & 15;
  int m0 = bm * 128, d0 = bn * 64;

  __shared__ u16 Yt[128][72];
  __shared__ u16 Wt[64][72];

  f32x4 acc[4];
#pragma unroll
  for (int ct = 0; ct < 4; ++ct) acc[ct] = (f32x4){0.f, 0.f, 0.f, 0.f};

  ushort4 py[4], pw[2];
#pragma unroll
  for (int i = 0; i < 4; ++i) {
    int f = tid + 512 * i; int r = f >> 4, cq = f & 15;
    py[i] = *(const ushort4*)(Yg + (size_t)(m0 + r) * 1024 + 4 * cq);
  }
#pragma unroll
  for (int i = 0; i < 2; ++i) {
    int f = tid + 512 * i; int r = f >> 4, cq = f & 15;
    pw[i] = *(const ushort4*)(WoutB + (size_t)(d0 + r) * 1024 + 4 * cq);
  }

  for (int kt = 0; kt < 16; ++kt) {
    __syncthreads();
#pragma unroll
    for (int i = 0; i < 4; ++i) {
      int f = tid + 512 * i; int r = f >> 4, cq = f & 15;
      *(ushort4*)&Yt[r][4 * cq] = py[i];
    }
#pragma unroll
    for (int i = 0; i < 2; ++i) {
      int f = tid + 512 * i; int r = f >> 4, cq = f & 15;
      *(ushort4*)&Wt[r][4 * cq] = pw[i];
    }
    __syncthreads();

    if (kt < 15) {
      int k1 = (kt + 1) * 64;
#pragma unroll
      for (int i = 0; i < 4; ++i) {
        int f = tid + 512 * i; int r = f >> 4, cq = f & 15;
        py[i] = *(const ushort4*)(Yg + (size_t)(m0 + r) * 1024 + k1 + 4 * cq);
      }
#pragma unroll
      for (int i = 0; i < 2; ++i) {
        int f = tid + 512 * i; int r = f >> 4, cq = f & 15;
        pw[i] = *(const ushort4*)(WoutB + (size_t)(d0 + r) * 1024 + k1 + 4 * cq);
      }
    }

    bf16x8 a0 = *(const bf16x8*)&Yt[16 * w + lr][q * 8];
    bf16x8 a1 = *(const bf16x8*)&Yt[16 * w + lr][32 + q * 8];
#pragma unroll
    for (int ct = 0; ct < 4; ++ct) {
      bf16x8 b0 = *(const bf16x8*)&Wt[16 * ct + lr][q * 8];
      bf16x8 b1 = *(const bf16x8*)&Wt[16 * ct + lr][32 + q * 8];
      acc[ct] = __builtin_amdgcn_mfma_f32_16x16x32_bf16(a0, b0, acc[ct], 0, 0, 0);
      acc[ct] = __builtin_amdgcn_mfma_f32_16x16x32_bf16(a1, b1, acc[ct], 0, 0, 0);
    }
  }

#pragma unroll
  for (int ct = 0; ct < 4; ++ct) {
    int d = d0 + 16 * ct + lr;
    float bo = bout[d];
#pragma unroll
    for (int r = 0; r < 4; ++r) {
      int m = m0 + 16 * w + q * 4 + r;
      out[(size_t)m * 1024 + d] = acc[ct][r] + bo;
    }
  }
}

// ---------------- host launcher ----------------
extern "C" void kernel_launch(void* const* d_in, const int* in_sizes, int n_in,
                              void* d_out, int out_size, void* d_ws, size_t ws_size,
                              hipStream_t stream)
{
  const float* inp   = (const float*)d_in[0];
  const float* WlogA = (const float*)d_in[1];
  const float* blogA = (const float*)d_in[2];
  const float* WXBC  = (const float*)d_in[3];
  const float* bXBC  = (const float*)d_in[4];
  const float* Wgate = (const float*)d_in[5];
  const float* bgate = (const float*)d_in[6];
  const float* Wout  = (const float*)d_in[7];
  const float* bout  = (const float*)d_in[8];
  float* out = (float*)d_out;

  const size_t SZ = (size_t)2 * 16 * 1024 * 64;  // 2,097,152 elements
  float* logAs  = (float*)d_ws;                  // 128 KiB
  float* rowexp = logAs + 32768;                 // 128 KiB
  float* colexp = rowexp + 32768;                // 128 KiB
  float* G      = colexp + 32768;                // 32*16*4096 f32 = 8 MiB
  u16* base16  = (u16*)(G + (size_t)32 * 16 * 4096);
  u16* XsT   = base16;          // [bh][c][t]      4 MiB
  u16* Bms   = XsT + SZ;        // [bh][t][n]      4 MiB
  u16* BmsT  = Bms + SZ;        // [bh][n][t]      4 MiB
  u16* Cms   = BmsT + SZ;       //                 4 MiB
  u16* gates = Cms + SZ;        // [b,t,h,c]       4 MiB
  u16* Yg    = gates + SZ;      // [b,t,d]         4 MiB
  u16* WoutB = Yg + SZ;         // bf16 Wout       2 MiB
  u16* HpreT = WoutB + 1024 * 1024;  // [bh][it][c][n]  4 MiB  (~38.4 MiB total)

  k_proj<<<dim3(32, 16), 256, 0, stream>>>(inp, WXBC, bXBC, Wgate, bgate,
                                           WlogA, blogA, XsT, Bms, BmsT, Cms,
                                           gates, logAs);
  k_scan<<<32, 1024, 0, stream>>>(logAs, rowexp, colexp, Wout, WoutB);
  k_state<<<dim3(16, 32), 256, 0, stream>>>(XsT, BmsT, colexp, G);
  k_prefix<<<32, 1024, 0, stream>>>(G, HpreT);
  k_ssm2<<<dim3(16, 32), 256, 0, stream>>>(XsT, Bms, Cms, rowexp, colexp,
                                           HpreT, gates, Yg);
  k_out<<<dim3(16, 16), 512, 0, stream>>>(Yg, WoutB, bout, out);
}

// Round 8
// 127.578 us; speedup vs baseline: 6.0047x; 1.0064x over previous
//
#include <hip/hip_runtime.h>

typedef unsigned int   u32;
typedef unsigned short u16;
typedef __attribute__((ext_vector_type(8))) short bf16x8;
typedef __attribute__((ext_vector_type(4))) float f32x4;

// ---------- bf16 helpers ----------
__device__ __forceinline__ float bfs(u16 u) {
  union { u32 i; float f; } v; v.i = ((u32)u) << 16; return v.f;
}
__device__ __forceinline__ u16 f2bf(float f) {
  union { float f; u32 i; } v; v.f = f;
  u32 r = v.i + 0x7fffu + ((v.i >> 16) & 1u);   // RNE
  return (u16)(r >> 16);
}
__device__ __forceinline__ ushort4 f2bf4(float4 v) {
  ushort4 p; p.x = f2bf(v.x); p.y = f2bf(v.y); p.z = f2bf(v.z); p.w = f2bf(v.w);
  return p;
}

// ---------------- Kernel 0: one-shot weight conversion f32 -> bf16 -----------
// slots: [0,49152) WXBC, [49152,65536) Wgate, [65536,327680) Wout  (float4 units)
__global__ __launch_bounds__(256) void k_prep(
    const float* __restrict__ WXBC, const float* __restrict__ Wgate,
    const float* __restrict__ Wout,
    u16* __restrict__ WXBCb, u16* __restrict__ Wgateb, u16* __restrict__ WoutB)
{
  int i = blockIdx.x * 256 + threadIdx.x;
  if (i < 49152) {
    ((ushort4*)WXBCb)[i] = f2bf4(((const float4*)WXBC)[i]);
  } else if (i < 65536) {
    int j = i - 49152;
    ((ushort4*)Wgateb)[j] = f2bf4(((const float4*)Wgate)[j]);
  } else {
    int j = i - 65536;
    ((ushort4*)WoutB)[j] = f2bf4(((const float4*)Wout)[j]);
  }
}

// ---------------- Kernel 1: projections — MFMA 16x16x32 bf16 ----------------
// grid (token-tile=32, head=16), 256 threads (4 waves). Weights pre-bf16.
__global__ __launch_bounds__(256) void k_proj(
    const float* __restrict__ inp,
    const u16* __restrict__ WXBCb,  const float* __restrict__ b_XBC,
    const u16* __restrict__ Wgateb, const float* __restrict__ b_gate,
    const float* __restrict__ W_logA, const float* __restrict__ b_logA,
    u16* __restrict__ XsT, u16* __restrict__ Bms, u16* __restrict__ BmsT,
    u16* __restrict__ Cms, u16* __restrict__ gates, float* __restrict__ logAs)
{
  int tt = blockIdx.x, h = blockIdx.y;
  int tid = threadIdx.x;
  int w = tid >> 6, l = tid & 63, q = l >> 4, lr = l & 15;
  int m0 = tt * 64;
  int b = m0 >> 10, tl0 = m0 & 1023;
  int bh = b * 16 + h;

  __shared__ u16 Xt[64][72];
  __shared__ u16 Wt[256][72];
  __shared__ float wl[64];

  if (tid < 64) wl[tid] = W_logA[h * 64 + tid];
#pragma unroll
  for (int i = 0; i < 4; ++i) {
    int f = tid + 256 * i; int r = f >> 4, cq = f & 15;
    float4 xv = *(const float4*)(inp + (size_t)(m0 + r) * 1024 + h * 64 + 4 * cq);
    *(ushort4*)&Xt[r][4 * cq] = f2bf4(xv);
  }
#pragma unroll
  for (int i = 0; i < 16; ++i) {   // 4096 ushort4 slots: 256 rows x 16
    int f = tid + 256 * i; int r = f >> 4, cq = f & 15;
    const u16* ws = (r < 192) ? (WXBCb + ((size_t)h * 192 + r) * 64)
                              : (Wgateb + ((size_t)h * 64 + (r - 192)) * 64);
    *(ushort4*)&Wt[r][4 * cq] = *(const ushort4*)(ws + 4 * cq);
  }
  __syncthreads();

  bf16x8 af[4][2];
#pragma unroll
  for (int rt = 0; rt < 4; ++rt) {
    af[rt][0] = *(const bf16x8*)&Xt[16 * rt + lr][q * 8];
    af[rt][1] = *(const bf16x8*)&Xt[16 * rt + lr][32 + q * 8];
  }

  f32x4 acc[4][4];
#pragma unroll
  for (int rt = 0; rt < 4; ++rt)
#pragma unroll
    for (int ct = 0; ct < 4; ++ct) acc[rt][ct] = (f32x4){0.f, 0.f, 0.f, 0.f};

#pragma unroll
  for (int ct = 0; ct < 4; ++ct) {
    bf16x8 b0 = *(const bf16x8*)&Wt[64 * w + 16 * ct + lr][q * 8];
    bf16x8 b1 = *(const bf16x8*)&Wt[64 * w + 16 * ct + lr][32 + q * 8];
#pragma unroll
    for (int rt = 0; rt < 4; ++rt) {
      acc[rt][ct] = __builtin_amdgcn_mfma_f32_16x16x32_bf16(af[rt][0], b0, acc[rt][ct], 0, 0, 0);
      acc[rt][ct] = __builtin_amdgcn_mfma_f32_16x16x32_bf16(af[rt][1], b1, acc[rt][ct], 0, 0, 0);
    }
  }

  if (tid < 64) {
    float a = b_logA[h];
#pragma unroll 16
    for (int k = 0; k < 64; ++k) a += bfs(Xt[tid][k]) * wl[k];
    logAs[(size_t)bh * 1024 + tl0 + tid] = a;
  }

  if (w == 0) {
    // X: silu, transposed store X^T[bh][n][t]
#pragma unroll
    for (int ct = 0; ct < 4; ++ct) {
      int n = 16 * ct + lr;
      float bias = b_XBC[h * 192 + n];
#pragma unroll
      for (int rt = 0; rt < 4; ++rt) {
        float4 v;
#pragma unroll
        for (int r = 0; r < 4; ++r) {
          float s = acc[rt][ct][r] + bias;
          (&v.x)[r] = s / (1.f + __expf(-s));
        }
        *(ushort4*)(XsT + ((size_t)bh * 64 + n) * 1024 + tl0 + 16 * rt + q * 4) = f2bf4(v);
      }
    }
  } else if (w == 1) {
    // B: silu, both [t][n] and [n][t]
#pragma unroll
    for (int ct = 0; ct < 4; ++ct) {
      int n = 16 * ct + lr;
      float bias = b_XBC[h * 192 + 64 + n];
#pragma unroll
      for (int rt = 0; rt < 4; ++rt) {
        float4 v;
#pragma unroll
        for (int r = 0; r < 4; ++r) {
          float s = acc[rt][ct][r] + bias;
          (&v.x)[r] = s / (1.f + __expf(-s));
        }
        ushort4 pv = f2bf4(v);
        *(ushort4*)(BmsT + ((size_t)bh * 64 + n) * 1024 + tl0 + 16 * rt + q * 4) = pv;
        u16 vs[4] = {pv.x, pv.y, pv.z, pv.w};
#pragma unroll
        for (int r = 0; r < 4; ++r) {
          int tloc = tl0 + 16 * rt + q * 4 + r;
          Bms[((size_t)bh * 1024 + tloc) * 64 + n] = vs[r];
        }
      }
    }
  } else if (w == 2) {
#pragma unroll
    for (int ct = 0; ct < 4; ++ct) {
      int n = 16 * ct + lr;
      float bias = b_XBC[h * 192 + 128 + n];
#pragma unroll
      for (int rt = 0; rt < 4; ++rt)
#pragma unroll
        for (int r = 0; r < 4; ++r) {
          int tloc = tl0 + 16 * rt + q * 4 + r;
          float s = acc[rt][ct][r] + bias;
          s = s / (1.f + __expf(-s));
          Cms[((size_t)bh * 1024 + tloc) * 64 + n] = f2bf(s);
        }
    }
  } else {
#pragma unroll
    for (int ct = 0; ct < 4; ++ct) {
      int n = 16 * ct + lr;
      float bias = b_gate[h * 64 + n];
#pragma unroll
      for (int rt = 0; rt < 4; ++rt)
#pragma unroll
        for (int r = 0; r < 4; ++r) {
          int tg = m0 + 16 * rt + q * 4 + r;
          gates[((size_t)tg * 16 + h) * 64 + n] = f2bf(acc[rt][ct][r] + bias);
        }
    }
  }
}

// ---------------- Kernel 2: fused scan + state MFMA + prefix -> HpreT --------
// grid 32 (bh), 1024 threads (16 waves). Wave jt owns state tile jt.
__global__ __launch_bounds__(1024) void k_mid(
    const float* __restrict__ logAs,
    const u16* __restrict__ XsT, const u16* __restrict__ BmsT,
    float* __restrict__ rowexp, float* __restrict__ colexp,
    u16* __restrict__ HpreT)
{
  int bh = blockIdx.x;
  int t = threadIdx.x;
  int wv = t >> 6, ln = t & 63;
  int q = ln >> 4, lr = ln & 15;

  __shared__ float wsum[16];
  __shared__ float cl[1024];
  __shared__ u16 Lb[16][16][72];   // [jt][lr][pos]  bf16 state tiles

  // ---- scan ----
  float v = logAs[(size_t)bh * 1024 + t];
#pragma unroll
  for (int off = 1; off < 64; off <<= 1) {
    float n = __shfl_up(v, off, 64);
    if (ln >= off) v += n;
  }
  if (ln == 63) wsum[wv] = v;
  __syncthreads();
  if (wv == 0) {
    float s = (ln < 16) ? wsum[ln] : 0.f;
#pragma unroll
    for (int off = 1; off < 16; off <<= 1) {
      float n = __shfl_up(s, off, 64);
      if (ln >= off) s += n;
    }
    if (ln < 16) wsum[ln] = s;
  }
  __syncthreads();
  if (wv > 0) v += wsum[wv - 1];
  float ce = __expf(-v);
  rowexp[(size_t)bh * 1024 + t] = __expf(v);
  colexp[(size_t)bh * 1024 + t] = ce;
  cl[t] = ce;
  __syncthreads();

  // ---- state tile jt = wv: G = B^T · diag(colexp) · X  (register frags) ----
  int j0 = wv * 64;
  const u16* Bbase = BmsT + (size_t)bh * 64 * 1024;   // [n][t]
  const u16* Xbase = XsT + (size_t)bh * 64 * 1024;    // [c][t]

  f32x4 acc[4][4];
#pragma unroll
  for (int rt = 0; rt < 4; ++rt)
#pragma unroll
    for (int ct = 0; ct < 4; ++ct) acc[rt][ct] = (f32x4){0.f, 0.f, 0.f, 0.f};

#pragma unroll
  for (int ct = 0; ct < 4; ++ct) {
    // B-operand: X row c = 16ct+lr, scaled by colexp
    const u16* xr = Xbase + ((size_t)(16 * ct + lr)) * 1024 + j0;
    bf16x8 x0 = *(const bf16x8*)(xr + q * 8);
    bf16x8 x1 = *(const bf16x8*)(xr + 32 + q * 8);
    bf16x8 b0, b1;
#pragma unroll
    for (int jj = 0; jj < 8; ++jj) {
      b0[jj] = (short)f2bf(bfs((u16)x0[jj]) * cl[j0 + q * 8 + jj]);
      b1[jj] = (short)f2bf(bfs((u16)x1[jj]) * cl[j0 + 32 + q * 8 + jj]);
    }
#pragma unroll
    for (int rt = 0; rt < 4; ++rt) {
      const u16* br = Bbase + ((size_t)(16 * rt + lr)) * 1024 + j0;
      bf16x8 a0 = *(const bf16x8*)(br + q * 8);
      bf16x8 a1 = *(const bf16x8*)(br + 32 + q * 8);
      acc[rt][ct] = __builtin_amdgcn_mfma_f32_16x16x32_bf16(a0, b0, acc[rt][ct], 0, 0, 0);
      acc[rt][ct] = __builtin_amdgcn_mfma_f32_16x16x32_bf16(a1, b1, acc[rt][ct], 0, 0, 0);
    }
  }

  // ---- chunked exclusive prefix over jt (4 chunks of 1024 elems) ----
  // flat element = c*64 + n;  chunk ct covers c in [16ct,16ct+16)
  int l16 = t >> 6, pos = t & 63;
#pragma unroll
  for (int ct = 0; ct < 4; ++ct) {
    __syncthreads();   // previous chunk's Lb reads complete
#pragma unroll
    for (int rt = 0; rt < 4; ++rt) {
      ushort4 pv;
      pv.x = f2bf(acc[rt][ct][0]); pv.y = f2bf(acc[rt][ct][1]);
      pv.z = f2bf(acc[rt][ct][2]); pv.w = f2bf(acc[rt][ct][3]);
      *(ushort4*)&Lb[wv][lr][16 * rt + q * 4] = pv;
    }
    __syncthreads();
    float hsum = 0.f;
    size_t gbase = (size_t)bh * 16 * 4096 + ct * 1024 + t;
#pragma unroll
    for (int jt = 0; jt < 16; ++jt) {
      HpreT[gbase + (size_t)jt * 4096] = f2bf(hsum);
      hsum += bfs(Lb[jt][l16][pos]);
    }
  }
}

// ---------------- Kernel 3: diagonal quadratic + C·Hpre — MFMA ---------------
__global__ __launch_bounds__(256) void k_ssm2(
    const u16* __restrict__ XsT, const u16* __restrict__ Bms, const u16* __restrict__ Cms,
    const float* __restrict__ rowexp, const float* __restrict__ colexp,
    const u16* __restrict__ HpreT, const u16* __restrict__ gates, u16* __restrict__ Yg)
{
  int it = blockIdx.x, bh = blockIdx.y;
  int b = bh >> 4, h = bh & 15;
  int tid = threadIdx.x;
  int w = tid >> 6, l = tid & 63, q = l >> 4, lr = l & 15;
  int i0 = it * 64;

  __shared__ u16 Cts[64][72];
  __shared__ u16 Bts[64][72];
  __shared__ u16 Xts[64][72];
  __shared__ u16 Sts[64][72];
  __shared__ u16 HTt[64][72];
  __shared__ float ref_[64], cef[64];

  const u16* Cb = Cms + (size_t)bh * 1024 * 64;
  const u16* Bb = Bms + (size_t)bh * 1024 * 64;
  const u16* Xb = XsT + (size_t)bh * 64 * 1024;
  const u16* Hb = HpreT + ((size_t)bh * 16 + it) * 4096;

#pragma unroll
  for (int i = 0; i < 4; ++i) {
    int f = tid + 256 * i; int r = f >> 4, cq = f & 15;
    *(ushort4*)&Cts[r][4 * cq] = *(const ushort4*)(Cb + (size_t)(i0 + r) * 64 + 4 * cq);
    *(ushort4*)&Bts[r][4 * cq] = *(const ushort4*)(Bb + (size_t)(i0 + r) * 64 + 4 * cq);
    *(ushort4*)&Xts[r][4 * cq] = *(const ushort4*)(Xb + (size_t)r * 1024 + i0 + 4 * cq);
    *(ushort4*)&HTt[r][4 * cq] = *(const ushort4*)(Hb + r * 64 + 4 * cq);
  }
  if (tid < 64) {
    ref_[tid] = rowexp[(size_t)bh * 1024 + i0 + tid];
    cef[tid]  = colexp[(size_t)bh * 1024 + i0 + tid];
  }
  __syncthreads();

  bf16x8 ca0 = *(const bf16x8*)&Cts[16 * w + lr][q * 8];
  bf16x8 ca1 = *(const bf16x8*)&Cts[16 * w + lr][32 + q * 8];

#pragma unroll
  for (int ct = 0; ct < 4; ++ct) {
    f32x4 s = (f32x4){0.f, 0.f, 0.f, 0.f};
    bf16x8 b0 = *(const bf16x8*)&Bts[16 * ct + lr][q * 8];
    bf16x8 b1 = *(const bf16x8*)&Bts[16 * ct + lr][32 + q * 8];
    s = __builtin_amdgcn_mfma_f32_16x16x32_bf16(ca0, b0, s, 0, 0, 0);
    s = __builtin_amdgcn_mfma_f32_16x16x32_bf16(ca1, b1, s, 0, 0, 0);
    int jl = 16 * ct + lr;
    float cj = cef[jl];
#pragma unroll
    for (int r = 0; r < 4; ++r) {
      int il = 16 * w + q * 4 + r;
      float v = (jl > il) ? 0.f : s[r] * ref_[il] * cj;
      Sts[il][jl] = f2bf(v);
    }
  }

  bf16x8 sa0 = *(const bf16x8*)&Sts[16 * w + lr][q * 8];
  bf16x8 sa1 = *(const bf16x8*)&Sts[16 * w + lr][32 + q * 8];
  f32x4 accd[4], acco[4];
#pragma unroll
  for (int ct = 0; ct < 4; ++ct) {
    accd[ct] = (f32x4){0.f, 0.f, 0.f, 0.f};
    acco[ct] = (f32x4){0.f, 0.f, 0.f, 0.f};
    bf16x8 x0 = *(const bf16x8*)&Xts[16 * ct + lr][q * 8];
    bf16x8 x1 = *(const bf16x8*)&Xts[16 * ct + lr][32 + q * 8];
    accd[ct] = __builtin_amdgcn_mfma_f32_16x16x32_bf16(sa0, x0, accd[ct], 0, 0, 0);
    accd[ct] = __builtin_amdgcn_mfma_f32_16x16x32_bf16(sa1, x1, accd[ct], 0, 0, 0);
    bf16x8 h0 = *(const bf16x8*)&HTt[16 * ct + lr][q * 8];
    bf16x8 h1 = *(const bf16x8*)&HTt[16 * ct + lr][32 + q * 8];
    acco[ct] = __builtin_amdgcn_mfma_f32_16x16x32_bf16(ca0, h0, acco[ct], 0, 0, 0);
    acco[ct] = __builtin_amdgcn_mfma_f32_16x16x32_bf16(ca1, h1, acco[ct], 0, 0, 0);
  }

#pragma unroll
  for (int ct = 0; ct < 4; ++ct) {
    int c = 16 * ct + lr;
#pragma unroll
    for (int r = 0; r < 4; ++r) {
      int il = 16 * w + q * 4 + r;
      int tg = i0 + il;
      size_t row = (size_t)(b * 1024 + tg);
      float y = accd[ct][r] + ref_[il] * acco[ct][r];
      float gt = bfs(gates[(row * 16 + h) * 64 + c]);
      Yg[row * 1024 + h * 64 + c] = f2bf(y * gt);
    }
  }
}

// ---------------- Kernel 4: out = Yg @ W_out^T + b_out — MFMA, 8 waves -------
__global__ __launch_bounds__(512) void k_out(
    const u16* __restrict__ Yg, const u16* __restrict__ WoutB,
    const float* __restrict__ bout, float* __restrict__ out)
{
  int bm = blockIdx.x, bn = blockIdx.y;
  int tid = threadIdx.x;
  int w = tid >> 6, l = tid & 63, q = l >> 4, lr = l & 15;
  int m0 = bm * 128, d0 = bn * 64;

  __shared__ u16 Yt[128][72];
  __shared__ u16 Wt[64][72];

  f32x4 acc[4];
#pragma unroll
  for (int ct = 0; ct < 4; ++ct) acc[ct] = (f32x4){0.f, 0.f, 0.f, 0.f};

  ushort4 py[4], pw[2];
#pragma unroll
  for (int i = 0; i < 4; ++i) {
    int f = tid + 512 * i; int r = f >> 4, cq = f & 15;
    py[i] = *(const ushort4*)(Yg + (size_t)(m0 + r) * 1024 + 4 * cq);
  }
#pragma unroll
  for (int i = 0; i < 2; ++i) {
    int f = tid + 512 * i; int r = f >> 4, cq = f & 15;
    pw[i] = *(const ushort4*)(WoutB + (size_t)(d0 + r) * 1024 + 4 * cq);
  }

  for (int kt = 0; kt < 16; ++kt) {
    __syncthreads();
#pragma unroll
    for (int i = 0; i < 4; ++i) {
      int f = tid + 512 * i; int r = f >> 4, cq = f & 15;
      *(ushort4*)&Yt[r][4 * cq] = py[i];
    }
#pragma unroll
    for (int i = 0; i < 2; ++i) {
      int f = tid + 512 * i; int r = f >> 4, cq = f & 15;
      *(ushort4*)&Wt[r][4 * cq] = pw[i];
    }
    __syncthreads();

    if (kt < 15) {
      int k1 = (kt + 1) * 64;
#pragma unroll
      for (int i = 0; i < 4; ++i) {
        int f = tid + 512 * i; int r = f >> 4, cq = f & 15;
        py[i] = *(const ushort4*)(Yg + (size_t)(m0 + r) * 1024 + k1 + 4 * cq);
      }
#pragma unroll
      for (int i = 0; i < 2; ++i) {
        int f = tid + 512 * i; int r = f >> 4, cq = f & 15;
        pw[i] = *(const ushort4*)(WoutB + (size_t)(d0 + r) * 1024 + k1 + 4 * cq);
      }
    }

    bf16x8 a0 = *(const bf16x8*)&Yt[16 * w + lr][q * 8];
    bf16x8 a1 = *(const bf16x8*)&Yt[16 * w + lr][32 + q * 8];
#pragma unroll
    for (int ct = 0; ct < 4; ++ct) {
      bf16x8 b0 = *(const bf16x8*)&Wt[16 * ct + lr][q * 8];
      bf16x8 b1 = *(const bf16x8*)&Wt[16 * ct + lr][32 + q * 8];
      acc[ct] = __builtin_amdgcn_mfma_f32_16x16x32_bf16(a0, b0, acc[ct], 0, 0, 0);
      acc[ct] = __builtin_amdgcn_mfma_f32_16x16x32_bf16(a1, b1, acc[ct], 0, 0, 0);
    }
  }

#pragma unroll
  for (int ct = 0; ct < 4; ++ct) {
    int d = d0 + 16 * ct + lr;
    float bo = bout[d];
#pragma unroll
    for (int r = 0; r < 4; ++r) {
      int m = m0 + 16 * w + q * 4 + r;
      out[(size_t)m * 1024 + d] = acc[ct][r] + bo;
    }
  }
}

// ---------------- host launcher ----------------
extern "C" void kernel_launch(void* const* d_in, const int* in_sizes, int n_in,
                              void* d_out, int out_size, void* d_ws, size_t ws_size,
                              hipStream_t stream)
{
  const float* inp   = (const float*)d_in[0];
  const float* WlogA = (const float*)d_in[1];
  const float* blogA = (const float*)d_in[2];
  const float* WXBC  = (const float*)d_in[3];
  const float* bXBC  = (const float*)d_in[4];
  const float* Wgate = (const float*)d_in[5];
  const float* bgate = (const float*)d_in[6];
  const float* Wout  = (const float*)d_in[7];
  const float* bout  = (const float*)d_in[8];
  float* out = (float*)d_out;

  const size_t SZ = (size_t)2 * 16 * 1024 * 64;  // 2,097,152 elements
  float* logAs  = (float*)d_ws;                  // 128 KiB
  float* rowexp = logAs + 32768;                 // 128 KiB
  float* colexp = rowexp + 32768;                // 128 KiB
  u16* base16  = (u16*)(colexp + 32768);
  u16* XsT    = base16;            // [bh][c][t]      4 MiB
  u16* Bms    = XsT + SZ;          // [bh][t][n]      4 MiB
  u16* BmsT   = Bms + SZ;          // [bh][n][t]      4 MiB
  u16* Cms    = BmsT + SZ;         //                 4 MiB
  u16* gates  = Cms + SZ;          // [b,t,h,c]       4 MiB
  u16* Yg     = gates + SZ;        // [b,t,d]         4 MiB
  u16* WoutB  = Yg + SZ;           // 1Mi u16         2 MiB
  u16* HpreT  = WoutB + 1024 * 1024;         // [bh][it][c][n]  4 MiB
  u16* WXBCb  = HpreT + (size_t)32 * 16 * 4096;  // 196608 u16
  u16* Wgateb = WXBCb + 196608;                  // 65536 u16  (~30.8 MiB total)

  k_prep<<<1280, 256, 0, stream>>>(WXBC, Wgate, Wout, WXBCb, Wgateb, WoutB);
  k_proj<<<dim3(32, 16), 256, 0, stream>>>(inp, WXBCb, bXBC, Wgateb, bgate,
                                           WlogA, blogA, XsT, Bms, BmsT, Cms,
                                           gates, logAs);
  k_mid<<<32, 1024, 0, stream>>>(logAs, XsT, BmsT, rowexp, colexp, HpreT);
  k_ssm2<<<dim3(16, 32), 256, 0, stream>>>(XsT, Bms, Cms, rowexp, colexp,
                                           HpreT, gates, Yg);
  k_out<<<dim3(16, 16), 512, 0, stream>>>(Yg, WoutB, bout, out);
}

// Round 9
// 118.420 us; speedup vs baseline: 6.4691x; 1.0773x over previous
//
#include <hip/hip_runtime.h>

typedef unsigned int   u32;
typedef unsigned short u16;
typedef __attribute__((ext_vector_type(8))) short bf16x8;
typedef __attribute__((ext_vector_type(4))) float f32x4;

// ---------- bf16 helpers ----------
__device__ __forceinline__ float bfs(u16 u) {
  union { u32 i; float f; } v; v.i = ((u32)u) << 16; return v.f;
}
__device__ __forceinline__ u16 f2bf(float f) {
  union { float f; u32 i; } v; v.f = f;
  u32 r = v.i + 0x7fffu + ((v.i >> 16) & 1u);   // RNE
  return (u16)(r >> 16);
}
__device__ __forceinline__ ushort4 f2bf4(float4 v) {
  ushort4 p; p.x = f2bf(v.x); p.y = f2bf(v.y); p.z = f2bf(v.z); p.w = f2bf(v.w);
  return p;
}

// ---------------- Kernel 1: projections + local scan + chunk state ----------
// grid (chunk tt=32, head=16), 256 threads (4 waves). Wave w owns out-group w
// (0=X, 1=B, 2=C, 3=gate). All global stores packed ushort4 via LDS transpose.
// Also: local 64-token logA scan (lexp/linv/dec) and chunk state
// G[bh][jt][c][n] = sum_t X[t][c]*exp(L-l_t)*B[t][n]  (f32).
__global__ __launch_bounds__(256) void k_proj(
    const float* __restrict__ inp,
    const float* __restrict__ W_XBC,  const float* __restrict__ b_XBC,
    const float* __restrict__ W_gate, const float* __restrict__ b_gate,
    const float* __restrict__ W_logA, const float* __restrict__ b_logA,
    const float* __restrict__ Wout, u16* __restrict__ WoutB,
    u16* __restrict__ XsT, u16* __restrict__ BmsT, u16* __restrict__ CmsT,
    u16* __restrict__ gatesP, float* __restrict__ lexp, float* __restrict__ linv,
    float* __restrict__ decArr, float* __restrict__ G)
{
  int tt = blockIdx.x, h = blockIdx.y;
  int tid = threadIdx.x;
  int w = tid >> 6, l = tid & 63, q = l >> 4, lr = l & 15;
  int m0 = tt * 64;
  int b = m0 >> 10, tl0 = m0 & 1023;
  int bh = b * 16 + h;
  int jt = tt & 15;

  __shared__ u16 Xt[64][72];
  __shared__ u16 Wt[256][72];
  __shared__ float wl[64];
  __shared__ float sg[64];

  // Wout f32->bf16, sliced across the 512 blocks (512 float4 each)
  {
    int fid = h * 32 + tt;
    const float4* src = (const float4*)Wout + (size_t)fid * 512;
    ushort4* dst = (ushort4*)WoutB + (size_t)fid * 512;
    for (int i = tid; i < 512; i += 256) dst[i] = f2bf4(src[i]);
  }

  if (tid < 64) wl[tid] = W_logA[h * 64 + tid];
#pragma unroll
  for (int i = 0; i < 4; ++i) {
    int f = tid + 256 * i; int r = f >> 4, cq = f & 15;
    float4 xv = *(const float4*)(inp + (size_t)(m0 + r) * 1024 + h * 64 + 4 * cq);
    *(ushort4*)&Xt[r][4 * cq] = f2bf4(xv);
  }
#pragma unroll
  for (int i = 0; i < 16; ++i) {   // weights (inline f32->bf16)
    int f = tid + 256 * i; int r = f >> 4, cq = f & 15;
    const float* ws = (r < 192) ? (W_XBC + ((size_t)h * 192 + r) * 64)
                                : (W_gate + ((size_t)h * 64 + (r - 192)) * 64);
    *(ushort4*)&Wt[r][4 * cq] = f2bf4(*(const float4*)(ws + 4 * cq));
  }
  __syncthreads();

  bf16x8 af[4][2];
#pragma unroll
  for (int rt = 0; rt < 4; ++rt) {
    af[rt][0] = *(const bf16x8*)&Xt[16 * rt + lr][q * 8];
    af[rt][1] = *(const bf16x8*)&Xt[16 * rt + lr][32 + q * 8];
  }

  f32x4 acc[4][4];
#pragma unroll
  for (int rt = 0; rt < 4; ++rt)
#pragma unroll
    for (int ct = 0; ct < 4; ++ct) acc[rt][ct] = (f32x4){0.f, 0.f, 0.f, 0.f};

#pragma unroll
  for (int ct = 0; ct < 4; ++ct) {
    bf16x8 b0 = *(const bf16x8*)&Wt[64 * w + 16 * ct + lr][q * 8];
    bf16x8 b1 = *(const bf16x8*)&Wt[64 * w + 16 * ct + lr][32 + q * 8];
#pragma unroll
    for (int rt = 0; rt < 4; ++rt) {
      acc[rt][ct] = __builtin_amdgcn_mfma_f32_16x16x32_bf16(af[rt][0], b0, acc[rt][ct], 0, 0, 0);
      acc[rt][ct] = __builtin_amdgcn_mfma_f32_16x16x32_bf16(af[rt][1], b1, acc[rt][ct], 0, 0, 0);
    }
  }

  // ---- local logA + 64-token inclusive scan (wave 0) ----
  if (tid < 64) {
    float a = b_logA[h];
#pragma unroll 16
    for (int k = 0; k < 64; ++k) a += bfs(Xt[tid][k]) * wl[k];
    float lv = a;
#pragma unroll
    for (int off = 1; off < 64; off <<= 1) {
      float n = __shfl_up(lv, off, 64);
      if (tid >= off) lv += n;
    }
    float L = __shfl(lv, 63, 64);
    sg[tid] = __expf(L - lv);
    lexp[(size_t)bh * 1024 + tl0 + tid] = __expf(lv);
    linv[(size_t)bh * 1024 + tl0 + tid] = __expf(-lv);
    if (tid == 63) decArr[bh * 16 + jt] = __expf(L);
  }

  // ---- bias + activation in registers ----
  if (w < 3) {
#pragma unroll
    for (int ct = 0; ct < 4; ++ct) {
      float bias = b_XBC[h * 192 + 64 * w + 16 * ct + lr];
#pragma unroll
      for (int rt = 0; rt < 4; ++rt)
#pragma unroll
        for (int r = 0; r < 4; ++r) {
          float s = acc[rt][ct][r] + bias;
          acc[rt][ct][r] = s / (1.f + __expf(-s));
        }
    }
  } else {
#pragma unroll
    for (int ct = 0; ct < 4; ++ct) {
      float bias = b_gate[h * 64 + 16 * ct + lr];
#pragma unroll
      for (int rt = 0; rt < 4; ++rt)
#pragma unroll
        for (int r = 0; r < 4; ++r) acc[rt][ct][r] += bias;
    }
  }
  __syncthreads();   // Wt frags consumed, sg ready -> reuse Wt as transpose buf

  // ---- transpose into Wt rows [64w, 64w+64) ----
  // w<3: [chan][t]; w==3: [t][chan]
  {
    u16* T = &Wt[64 * w][0];
#pragma unroll
    for (int ct = 0; ct < 4; ++ct)
#pragma unroll
      for (int rt = 0; rt < 4; ++rt)
#pragma unroll
        for (int r = 0; r < 4; ++r) {
          int t = 16 * rt + 4 * q + r, n = 16 * ct + lr;
          u16 v = f2bf(acc[rt][ct][r]);
          if (w < 3) T[n * 72 + t] = v;
          else       T[t * 72 + n] = v;
        }
  }
  __syncthreads();

  // ---- packed global stores ----
  {
#pragma unroll
    for (int i = 0; i < 16; ++i) {
      int s = l + 64 * i; int row = s >> 4, cq = s & 15;
      ushort4 v = *(ushort4*)&Wt[64 * w + row][4 * cq];
      if (w == 0)
        *(ushort4*)(XsT + ((size_t)bh * 64 + row) * 1024 + tl0 + 4 * cq) = v;
      else if (w == 1)
        *(ushort4*)(BmsT + ((size_t)bh * 64 + row) * 1024 + tl0 + 4 * cq) = v;
      else if (w == 2)
        *(ushort4*)(CmsT + ((size_t)bh * 64 + row) * 1024 + tl0 + 4 * cq) = v;
      else
        *(ushort4*)(gatesP + ((size_t)bh * 1024 + tl0 + row) * 64 + 4 * cq) = v;
    }
  }

  // ---- chunk state G[c][n] = sum_t X[t][c]*sg[t]*B[t][n] ----
  // A from Wt rows 0..63 (XtT [c][t], scaled); B-op from rows 64..127 (BtT [n][t]).
  {
    bf16x8 a0r = *(const bf16x8*)&Wt[16 * w + lr][q * 8];
    bf16x8 a1r = *(const bf16x8*)&Wt[16 * w + lr][32 + q * 8];
    bf16x8 a0, a1;
#pragma unroll
    for (int jj = 0; jj < 8; ++jj) {
      a0[jj] = (short)f2bf(bfs((u16)a0r[jj]) * sg[q * 8 + jj]);
      a1[jj] = (short)f2bf(bfs((u16)a1r[jj]) * sg[32 + q * 8 + jj]);
    }
    f32x4 gacc[4];
#pragma unroll
    for (int nt = 0; nt < 4; ++nt) {
      gacc[nt] = (f32x4){0.f, 0.f, 0.f, 0.f};
      bf16x8 bb0 = *(const bf16x8*)&Wt[64 + 16 * nt + lr][q * 8];
      bf16x8 bb1 = *(const bf16x8*)&Wt[64 + 16 * nt + lr][32 + q * 8];
      gacc[nt] = __builtin_amdgcn_mfma_f32_16x16x32_bf16(a0, bb0, gacc[nt], 0, 0, 0);
      gacc[nt] = __builtin_amdgcn_mfma_f32_16x16x32_bf16(a1, bb1, gacc[nt], 0, 0, 0);
    }
    float* Gt = G + ((size_t)bh * 16 + jt) * 4096;
#pragma unroll
    for (int nt = 0; nt < 4; ++nt)
#pragma unroll
      for (int r = 0; r < 4; ++r)
        Gt[(16 * w + 4 * q + r) * 64 + 16 * nt + lr] = gacc[nt][r];
  }
}

// ---------------- Kernel 2: state recurrence H_{k+1}=dec_k*H_k+G_k ----------
// grid (chunk-quarter=4, bh=32), 1024 threads; all 16 G values preloaded.
__global__ __launch_bounds__(1024) void k_mid(
    const float* __restrict__ G, const float* __restrict__ decArr,
    u16* __restrict__ HpreT)
{
  int cc = blockIdx.x, bh = blockIdx.y;
  int tid = threadIdx.x;
  int e = cc * 1024 + tid;          // flat [c][n]
  __shared__ float dsm[16];
  if (tid < 16) dsm[tid] = decArr[bh * 16 + tid];
  __syncthreads();
  const float* Gb = G + (size_t)bh * 16 * 4096 + e;
  float g[16];
#pragma unroll
  for (int jtl = 0; jtl < 16; ++jtl) g[jtl] = Gb[(size_t)jtl * 4096];
  u16* Hb = HpreT + (size_t)bh * 16 * 4096 + e;
  float hst = 0.f;
#pragma unroll
  for (int jtl = 0; jtl < 16; ++jtl) {
    Hb[(size_t)jtl * 4096] = f2bf(hst);
    hst = dsm[jtl] * hst + g[jtl];
  }
}

// ---------------- Kernel 3: diagonal quadratic + C·Hpre — MFMA ---------------
// grid (it=16, bh=32), 256 threads. All-local exps; B/C transposed in LDS.
__global__ __launch_bounds__(256) void k_ssm2(
    const u16* __restrict__ XsT, const u16* __restrict__ BmsT,
    const u16* __restrict__ CmsT,
    const float* __restrict__ lexp, const float* __restrict__ linv,
    const u16* __restrict__ HpreT, const u16* __restrict__ gatesP,
    u16* __restrict__ Yg)
{
  int it = blockIdx.x, bh = blockIdx.y;
  int b = bh >> 4, h = bh & 15;
  int tid = threadIdx.x;
  int w = tid >> 6, l = tid & 63, q = l >> 4, lr = l & 15;
  int i0 = it * 64;

  __shared__ u16 Cts[64][72];   // [t][n]
  __shared__ u16 Bts[64][72];   // [t][n]
  __shared__ u16 Xts[64][72];   // [c][t]
  __shared__ u16 HTt[64][72];   // [c][n]
  __shared__ u16 Gts[64][72];   // [t][c]
  __shared__ u16 Sts[64][72];
  __shared__ float ref_[64], cef[64];

  const u16* Xb  = XsT  + (size_t)bh * 64 * 1024;
  const u16* BbT = BmsT + (size_t)bh * 64 * 1024;
  const u16* CbT = CmsT + (size_t)bh * 64 * 1024;
  const u16* Hb  = HpreT + ((size_t)bh * 16 + it) * 4096;
  const u16* Gb  = gatesP + ((size_t)bh * 1024 + i0) * 64;

#pragma unroll
  for (int i = 0; i < 4; ++i) {
    int f = tid + 256 * i; int r = f >> 4, cq = f & 15;
    *(ushort4*)&Xts[r][4 * cq] = *(const ushort4*)(Xb + (size_t)r * 1024 + i0 + 4 * cq);
    *(ushort4*)&HTt[r][4 * cq] = *(const ushort4*)(Hb + r * 64 + 4 * cq);
    *(ushort4*)&Gts[r][4 * cq] = *(const ushort4*)(Gb + r * 64 + 4 * cq);
    ushort4 bv = *(const ushort4*)(BbT + (size_t)r * 1024 + i0 + 4 * cq);
    Bts[4 * cq + 0][r] = bv.x; Bts[4 * cq + 1][r] = bv.y;
    Bts[4 * cq + 2][r] = bv.z; Bts[4 * cq + 3][r] = bv.w;
    ushort4 cv = *(const ushort4*)(CbT + (size_t)r * 1024 + i0 + 4 * cq);
    Cts[4 * cq + 0][r] = cv.x; Cts[4 * cq + 1][r] = cv.y;
    Cts[4 * cq + 2][r] = cv.z; Cts[4 * cq + 3][r] = cv.w;
  }
  if (tid < 64) {
    ref_[tid] = lexp[(size_t)bh * 1024 + i0 + tid];
    cef[tid]  = linv[(size_t)bh * 1024 + i0 + tid];
  }
  __syncthreads();

  bf16x8 ca0 = *(const bf16x8*)&Cts[16 * w + lr][q * 8];
  bf16x8 ca1 = *(const bf16x8*)&Cts[16 * w + lr][32 + q * 8];

#pragma unroll
  for (int ct = 0; ct < 4; ++ct) {
    f32x4 s = (f32x4){0.f, 0.f, 0.f, 0.f};
    bf16x8 b0 = *(const bf16x8*)&Bts[16 * ct + lr][q * 8];
    bf16x8 b1 = *(const bf16x8*)&Bts[16 * ct + lr][32 + q * 8];
    s = __builtin_amdgcn_mfma_f32_16x16x32_bf16(ca0, b0, s, 0, 0, 0);
    s = __builtin_amdgcn_mfma_f32_16x16x32_bf16(ca1, b1, s, 0, 0, 0);
    int jl = 16 * ct + lr;
    float cj = cef[jl];
#pragma unroll
    for (int r = 0; r < 4; ++r) {
      int il = 16 * w + q * 4 + r;
      float v = (jl > il) ? 0.f : s[r] * ref_[il] * cj;
      Sts[il][jl] = f2bf(v);
    }
  }

  // Y = S·X_diag + diag(lexp)·(C·Hpre)   (same-wave Sts rows: no extra barrier)
  bf16x8 sa0 = *(const bf16x8*)&Sts[16 * w + lr][q * 8];
  bf16x8 sa1 = *(const bf16x8*)&Sts[16 * w + lr][32 + q * 8];
  f32x4 accd[4], acco[4];
#pragma unroll
  for (int ct = 0; ct < 4; ++ct) {
    accd[ct] = (f32x4){0.f, 0.f, 0.f, 0.f};
    acco[ct] = (f32x4){0.f, 0.f, 0.f, 0.f};
    bf16x8 x0 = *(const bf16x8*)&Xts[16 * ct + lr][q * 8];
    bf16x8 x1 = *(const bf16x8*)&Xts[16 * ct + lr][32 + q * 8];
    accd[ct] = __builtin_amdgcn_mfma_f32_16x16x32_bf16(sa0, x0, accd[ct], 0, 0, 0);
    accd[ct] = __builtin_amdgcn_mfma_f32_16x16x32_bf16(sa1, x1, accd[ct], 0, 0, 0);
    bf16x8 h0 = *(const bf16x8*)&HTt[16 * ct + lr][q * 8];
    bf16x8 h1 = *(const bf16x8*)&HTt[16 * ct + lr][32 + q * 8];
    acco[ct] = __builtin_amdgcn_mfma_f32_16x16x32_bf16(ca0, h0, acco[ct], 0, 0, 0);
    acco[ct] = __builtin_amdgcn_mfma_f32_16x16x32_bf16(ca1, h1, acco[ct], 0, 0, 0);
  }

#pragma unroll
  for (int ct = 0; ct < 4; ++ct) {
    int c = 16 * ct + lr;
#pragma unroll
    for (int r = 0; r < 4; ++r) {
      int il = 16 * w + q * 4 + r;
      int tg = i0 + il;
      size_t row = (size_t)(b * 1024 + tg);
      float y = accd[ct][r] + ref_[il] * acco[ct][r];
      float gt = bfs(Gts[il][c]);
      Yg[row * 1024 + h * 64 + c] = f2bf(y * gt);
    }
  }
}

// ---------------- Kernel 4: out = Yg @ W_out^T + b_out — MFMA, 8 waves -------
__global__ __launch_bounds__(512) void k_out(
    const u16* __restrict__ Yg, const u16* __restrict__ WoutB,
    const float* __restrict__ bout, float* __restrict__ out)
{
  int bm = blockIdx.x, bn = blockIdx.y;
  int tid = threadIdx.x;
  int w = tid >> 6, l = tid & 63, q = l >> 4, lr = l & 15;
  int m0 = bm * 128, d0 = bn * 64;

  __shared__ u16 Yt[128][72];
  __shared__ u16 Wt[64][72];

  f32x4 acc[4];
#pragma unroll
  for (int ct = 0; ct < 4; ++ct) acc[ct] = (f32x4){0.f, 0.f, 0.f, 0.f};

  ushort4 py[4], pw[2];
#pragma unroll
  for (int i = 0; i < 4; ++i) {
    int f = tid + 512 * i; int r = f >> 4, cq = f & 15;
    py[i] = *(const ushort4*)(Yg + (size_t)(m0 + r) * 1024 + 4 * cq);
  }
#pragma unroll
  for (int i = 0; i < 2; ++i) {
    int f = tid + 512 * i; int r = f >> 4, cq = f & 15;
    pw[i] = *(const ushort4*)(WoutB + (size_t)(d0 + r) * 1024 + 4 * cq);
  }

  for (int kt = 0; kt < 16; ++kt) {
    __syncthreads();
#pragma unroll
    for (int i = 0; i < 4; ++i) {
      int f = tid + 512 * i; int r = f >> 4, cq = f & 15;
      *(ushort4*)&Yt[r][4 * cq] = py[i];
    }
#pragma unroll
    for (int i = 0; i < 2; ++i) {
      int f = tid + 512 * i; int r = f >> 4, cq = f & 15;
      *(ushort4*)&Wt[r][4 * cq] = pw[i];
    }
    __syncthreads();

    if (kt < 15) {
      int k1 = (kt + 1) * 64;
#pragma unroll
      for (int i = 0; i < 4; ++i) {
        int f = tid + 512 * i; int r = f >> 4, cq = f & 15;
        py[i] = *(const ushort4*)(Yg + (size_t)(m0 + r) * 1024 + k1 + 4 * cq);
      }
#pragma unroll
      for (int i = 0; i < 2; ++i) {
        int f = tid + 512 * i; int r = f >> 4, cq = f & 15;
        pw[i] = *(const ushort4*)(WoutB + (size_t)(d0 + r) * 1024 + k1 + 4 * cq);
      }
    }

    bf16x8 a0 = *(const bf16x8*)&Yt[16 * w + lr][q * 8];
    bf16x8 a1 = *(const bf16x8*)&Yt[16 * w + lr][32 + q * 8];
#pragma unroll
    for (int ct = 0; ct < 4; ++ct) {
      bf16x8 b0 = *(const bf16x8*)&Wt[16 * ct + lr][q * 8];
      bf16x8 b1 = *(const bf16x8*)&Wt[16 * ct + lr][32 + q * 8];
      acc[ct] = __builtin_amdgcn_mfma_f32_16x16x32_bf16(a0, b0, acc[ct], 0, 0, 0);
      acc[ct] = __builtin_amdgcn_mfma_f32_16x16x32_bf16(a1, b1, acc[ct], 0, 0, 0);
    }
  }

#pragma unroll
  for (int ct = 0; ct < 4; ++ct) {
    int d = d0 + 16 * ct + lr;
    float bo = bout[d];
#pragma unroll
    for (int r = 0; r < 4; ++r) {
      int m = m0 + 16 * w + q * 4 + r;
      out[(size_t)m * 1024 + d] = acc[ct][r] + bo;
    }
  }
}

// ---------------- host launcher ----------------
extern "C" void kernel_launch(void* const* d_in, const int* in_sizes, int n_in,
                              void* d_out, int out_size, void* d_ws, size_t ws_size,
                              hipStream_t stream)
{
  const float* inp   = (const float*)d_in[0];
  const float* WlogA = (const float*)d_in[1];
  const float* blogA = (const float*)d_in[2];
  const float* WXBC  = (const float*)d_in[3];
  const float* bXBC  = (const float*)d_in[4];
  const float* Wgate = (const float*)d_in[5];
  const float* bgate = (const float*)d_in[6];
  const float* Wout  = (const float*)d_in[7];
  const float* bout  = (const float*)d_in[8];
  float* out = (float*)d_out;

  const size_t SZ = (size_t)2 * 16 * 1024 * 64;  // 2,097,152 elements
  float* lexp   = (float*)d_ws;                  // 32768 f32
  float* linv   = lexp + 32768;                  // 32768 f32
  float* decA   = linv + 32768;                  // 512 f32
  float* G      = decA + 512;                    // 32*16*4096 f32 = 8 MiB
  u16* base16 = (u16*)(G + (size_t)32 * 16 * 4096);
  u16* XsT    = base16;              // [bh][c][t]   4 MiB
  u16* BmsT   = XsT + SZ;            // [bh][n][t]   4 MiB
  u16* CmsT   = BmsT + SZ;           // [bh][n][t]   4 MiB
  u16* gatesP = CmsT + SZ;           // [bh][t][c]   4 MiB
  u16* Yg     = gatesP + SZ;         // [b,t,d]      4 MiB
  u16* WoutB  = Yg + SZ;             //              2 MiB
  u16* HpreT  = WoutB + 1024 * 1024; // [bh][it][c][n] 4 MiB  (~34.3 MiB total)

  k_proj<<<dim3(32, 16), 256, 0, stream>>>(inp, WXBC, bXBC, Wgate, bgate,
                                           WlogA, blogA, Wout, WoutB,
                                           XsT, BmsT, CmsT, gatesP,
                                           lexp, linv, decA, G);
  k_mid<<<dim3(4, 32), 1024, 0, stream>>>(G, decA, HpreT);
  k_ssm2<<<dim3(16, 32), 256, 0, stream>>>(XsT, BmsT, CmsT, lexp, linv,
                                           HpreT, gatesP, Yg);
  k_out<<<dim3(16, 16), 512, 0, stream>>>(Yg, WoutB, bout, out);
}